// Round 1
// 598.614 us; speedup vs baseline: 1.0433x; 1.0433x over previous
//
#include <hip/hip_runtime.h>
#include <hip/hip_bf16.h>

#define ND 2048

using bf16 = __hip_bfloat16;
using short8 = __attribute__((ext_vector_type(8))) short;   // 8 bf16 = 4 VGPRs
using floatx4 = __attribute__((ext_vector_type(4))) float;

// ---------------- async global->LDS (16B per lane, wave-uniform LDS base) ----
__device__ __forceinline__ void gl2lds16(const short* g, short* l) {
    __builtin_amdgcn_global_load_lds(
        (const __attribute__((address_space(1))) unsigned int*)g,
        (__attribute__((address_space(3))) unsigned int*)l,
        16, 0, 0);
}

// ---------------- elementwise kernels ----------------

// M = 0.5*(u^T - u) (this is A.T of the reference), fp32 in -> bf16 out.
__global__ void build_skew(const float* __restrict__ u, bf16* __restrict__ M) {
    __shared__ float t[32][33];
    const int bx = blockIdx.x & (ND / 32 - 1);
    const int by = blockIdx.x / (ND / 32);
    const int tx = threadIdx.x & 31;
    const int ty = threadIdx.x >> 5;   // 0..7
#pragma unroll
    for (int rr = 0; rr < 4; ++rr) {
        const int r = ty * 4 + rr;
        t[tx][r] = u[(size_t)(bx * 32 + r) * ND + by * 32 + tx];
    }
    __syncthreads();
#pragma unroll
    for (int rr = 0; rr < 4; ++rr) {
        const int r = ty * 4 + rr;
        const size_t idx = (size_t)(by * 32 + r) * ND + bx * 32 + tx;
        M[idx] = __float2bfloat16(0.5f * (t[r][tx] - u[idx]));
    }
}

// Hoff = 2M + Msq (may alias Msq same-index -> no __restrict__ on those)
__global__ void build_hoff1(const bf16* __restrict__ M, const bf16* Msq, bf16* Hoff) {
    const size_t idx = (size_t)blockIdx.x * 256 + threadIdx.x;
    const float m = __bfloat162float(M[idx]);
    const float q = __bfloat162float(Msq[idx]);
    Hoff[idx] = __float2bfloat16(2.f * m + q);
}

// Tier-B variant: also emits HoffT = -2M + Msq (HoffT may alias M)
__global__ void build_hoff(const bf16* M, const bf16* Msq, bf16* Hoff, bf16* HoffT) {
    const size_t idx = (size_t)blockIdx.x * 256 + threadIdx.x;
    const float m = __bfloat162float(M[idx]);
    const float q = __bfloat162float(Msq[idx]);
    Hoff[idx] = __float2bfloat16(2.f * m + q);
    HoffT[idx] = __float2bfloat16(q - 2.f * m);
}

// x fp32 -> bf16, 8 elems/thread
__global__ void convert_f32_bf16(const float* __restrict__ x, bf16* __restrict__ y) {
    const size_t base = ((size_t)blockIdx.x * 256 + threadIdx.x) * 8;
    const float4 f0 = *(const float4*)(x + base);
    const float4 f1 = *(const float4*)(x + base + 4);
    short8 pk;
    pk[0] = __builtin_bit_cast(short, __float2bfloat16(f0.x));
    pk[1] = __builtin_bit_cast(short, __float2bfloat16(f0.y));
    pk[2] = __builtin_bit_cast(short, __float2bfloat16(f0.z));
    pk[3] = __builtin_bit_cast(short, __float2bfloat16(f0.w));
    pk[4] = __builtin_bit_cast(short, __float2bfloat16(f1.x));
    pk[5] = __builtin_bit_cast(short, __float2bfloat16(f1.y));
    pk[6] = __builtin_bit_cast(short, __float2bfloat16(f1.z));
    pk[7] = __builtin_bit_cast(short, __float2bfloat16(f1.w));
    *(short8*)((short*)y + base) = pk;
}

// ---------------- epilogue modes ----------------
enum { EPI_PLAIN = 0, EPI_NEG = 1, EPI_ADD1 = 2, EPI_P = 3, EPI_P_ROT = 4, EPI_PT = 5 };
// EPI_PT: C = acc + I + add1 + add2^T   (transposed add2 read, kills HoffT buffer)

// ---------------- async-staged GEMM core: C = A @ Bt^T ----------------
// 128x128 tile, BK=32, 256 threads, global_load_lds dwordx4 staging (m97 structure).
template <int EPI, bool OF32>
__device__ __forceinline__ void gemm_core(
    short* aT, short* bT,
    const bf16* __restrict__ A, const bf16* __restrict__ Bt, void* __restrict__ Cp,
    const int Nc, const int K, const int bx, const int by,
    const bf16* __restrict__ add1, const bf16* __restrict__ add2,
    const float* __restrict__ thetaP)
{
    const int tid = threadIdx.x;
    const int lane = tid & 63;
    const int quad = lane >> 4;
    const int l15 = lane & 15;
    const int wv = tid >> 6;
    const int wr = (wv >> 1) << 6;   // wave row offset: 0 or 64
    const int wc = (wv & 1) << 6;    // wave col offset: 0 or 64

    const short* Ag = (const short*)A + (size_t)(by << 7) * K;
    const short* Bg = (const short*)Bt + (size_t)(bx << 7) * K;

    floatx4 acc[4][4];
#pragma unroll
    for (int i = 0; i < 4; ++i)
#pragma unroll
        for (int j = 0; j < 4; ++j)
            acc[i][j] = (floatx4){0.f, 0.f, 0.f, 0.f};

    for (int k0 = 0; k0 < K; k0 += 32) {
        // 128x32 tiles = 512 x 16B chunks each; 2 chunks/thread, async DMA.
        // chunk ch -> LDS shorts [ch*8, ch*8+8) ; wave-uniform base + lane*16B.
#pragma unroll
        for (int c = 0; c < 2; ++c) {
            const int ch = (c << 8) + (wv << 6) + lane;
            const int row = ch >> 2;
            const int kp = (ch & 3) << 3;                 // short offset in row
            const int ldsBase = ((c << 8) + (wv << 6)) << 3;  // shorts, wave-uniform
            gl2lds16(Ag + (size_t)row * K + k0 + kp, aT + ldsBase);
            gl2lds16(Bg + (size_t)row * K + k0 + kp, bT + ldsBase);
        }
        __syncthreads();
        short8 af[4], bfr[4];
#pragma unroll
        for (int mi = 0; mi < 4; ++mi)
            af[mi] = *(const short8*)(aT + ((wr + (mi << 4) + l15) << 5) + (quad << 3));
#pragma unroll
        for (int ni = 0; ni < 4; ++ni)
            bfr[ni] = *(const short8*)(bT + ((wc + (ni << 4) + l15) << 5) + (quad << 3));
#pragma unroll
        for (int mi = 0; mi < 4; ++mi)
#pragma unroll
            for (int ni = 0; ni < 4; ++ni)
                acc[mi][ni] = __builtin_amdgcn_mfma_f32_16x16x32_bf16(af[mi], bfr[ni], acc[mi][ni], 0, 0, 0);
        __syncthreads();
    }

    float ct = 0.f, st = 0.f;
    if (EPI == EPI_P_ROT) {
        const float th = *thetaP;
        ct = cosf(th);
        st = sinf(th);
    }

    // C/D layout (m89-verified): col = lane&15, row = quad*4 + reg
#pragma unroll
    for (int mi = 0; mi < 4; ++mi) {
#pragma unroll
        for (int ni = 0; ni < 4; ++ni) {
#pragma unroll
            for (int r = 0; r < 4; ++r) {
                const int row = (by << 7) + wr + (mi << 4) + (quad << 2) + r;
                const int col = (bx << 7) + wc + (ni << 4) + l15;
                const size_t idx = (size_t)row * Nc + col;
                float v = acc[mi][ni][r];
                if (EPI == EPI_NEG) v = -v;
                if (EPI == EPI_ADD1) v += __bfloat162float(add1[idx]);
                if (EPI == EPI_P)
                    v += (row == col ? 1.f : 0.f)
                       + __bfloat162float(add1[idx]) + __bfloat162float(add2[idx]);
                if (EPI == EPI_PT)
                    v += (row == col ? 1.f : 0.f)
                       + __bfloat162float(add1[idx])
                       + __bfloat162float(add2[(size_t)col * Nc + row]);
                if (EPI == EPI_P_ROT) {
                    v += (row == col ? 1.f : 0.f)
                       + __bfloat162float(add1[idx]) + __bfloat162float(add2[idx]);
                    const float w = __shfl_xor(v, 1, 64);
                    v = (l15 & 1) ? (st * w + ct * v) : (ct * v - st * w);
                }
                if (OF32) ((float*)Cp)[idx] = v;
                else      ((bf16*)Cp)[idx] = __float2bfloat16(v);
            }
        }
    }
}

template <int EPI, bool OF32>
__launch_bounds__(256, 2) __global__
void gemm_one(const bf16* __restrict__ A, const bf16* __restrict__ Bt,
              void* __restrict__ Cp, const int Nc, const int K,
              const bf16* __restrict__ add1, const bf16* __restrict__ add2,
              const float* __restrict__ thetaP)
{
    __shared__ __attribute__((aligned(16))) short aT[128 * 32];
    __shared__ __attribute__((aligned(16))) short bT[128 * 32];
    const int nblk = Nc >> 7;
    gemm_core<EPI, OF32>(aT, bT, A, Bt, Cp, Nc, K, blockIdx.x % nblk, blockIdx.x / nblk,
                         add1, add2, thetaP);
}

// Two independent 2048^2 GEMMs in one dispatch (grid = 512 -> 2 blocks/CU).
template <int EPI0, int EPI1>
__launch_bounds__(256, 2) __global__
void gemm_dual(const bf16* A0, const bf16* B0, bf16* C0, const bf16* a10, const bf16* a20,
               const bf16* A1, const bf16* B1, bf16* C1, const bf16* a11, const bf16* a21,
               const float* thetaP)
{
    __shared__ __attribute__((aligned(16))) short aT[128 * 32];
    __shared__ __attribute__((aligned(16))) short bT[128 * 32];
    const int nblk = ND >> 7;          // 16
    const int nsub = nblk * nblk;      // 256
    int b = blockIdx.x;
    if (b < nsub) {
        gemm_core<EPI0, false>(aT, bT, A0, B0, (void*)C0, ND, ND, b % nblk, b / nblk, a10, a20, thetaP);
    } else {
        b -= nsub;
        gemm_core<EPI1, false>(aT, bT, A1, B1, (void*)C1, ND, ND, b % nblk, b / nblk, a11, a21, thetaP);
    }
}

// ================== 256x256 / BK=64 / 8-phase / counted-vmcnt big GEMM =======
// C(fp32)[M][Nc] = A(bf16)[M][K] @ Bt(bf16)[Nc][K]^T
// 512 threads = 8 waves (2M x 4N); per-wave 128x64 output; LDS 128 KiB static
// (2 dbuf x (256x64) x {A,B}).  T2 chunk-XOR swizzle applied identically on the
// pre-swizzled global source (linear global_load_lds dest) and the ds_read addr.
// Staging stagger: tile T's halves issue at (T-2).p2 [A rows 0-63,128-191],
// (T-2).p3 [B rows 0-127], (T-2).p4 [B rows 128-255], (T-1).p1 [A rows 64-127,
// 192-255]; steady-state wait is vmcnt(6) once per K-tile (3 half-tiles = 6
// loads stay in flight across barriers), vmcnt(0) only for the last two tiles.

__device__ __forceinline__ void stage512(short* ldsT, const short* gT, const int K,
                                         const int kb, const int c0,
                                         const int wv, const int lane) {
    const int ch = c0 + (wv << 6) + lane;      // chunk index in 256x64 tile
    const int rw = ch >> 3;                    // row (8 chunks of 16B per row)
    const int cs = (ch & 7) ^ (rw & 7);        // inverse-swizzled source k-chunk
    gl2lds16(gT + (size_t)rw * K + kb + (cs << 3),
             ldsT + ((c0 + (wv << 6)) << 3));  // wave-uniform linear LDS dest
}

__device__ __forceinline__ void phase_mid() {
    __builtin_amdgcn_sched_barrier(0);
    __builtin_amdgcn_s_barrier();
    asm volatile("s_waitcnt lgkmcnt(0)" ::: "memory");
    __builtin_amdgcn_sched_barrier(0);
    __builtin_amdgcn_s_setprio(1);
}
__device__ __forceinline__ void phase_end() {
    __builtin_amdgcn_s_setprio(0);
    __builtin_amdgcn_sched_barrier(0);
    __builtin_amdgcn_s_barrier();
}

__device__ __forceinline__ void tile256(
    short* Ac, short* Bc, short* An,
    const short* Ag, const short* Bg, const int K, const int nt, const int t,
    const int wv, const int lane, const int aBase, const int bBase,
    const int cOff0, const int cOff1, floatx4 (&acc)[8][4])
{
    short8 af[4][2], bb[4][2];
    const int kb1 = (t + 1) << 6;
    const int kb2 = (t + 2) << 6;

    // ---- phase 1: ds_read A rows mi0-3 + B ni0-1 ; stage (t+1) A-part2 -> An
#pragma unroll
    for (int ml = 0; ml < 4; ++ml) {
        af[ml][0] = *(const short8*)(Ac + aBase + (ml << 10) + cOff0);
        af[ml][1] = *(const short8*)(Ac + aBase + (ml << 10) + cOff1);
    }
#pragma unroll
    for (int ni = 0; ni < 2; ++ni) {
        bb[ni][0] = *(const short8*)(Bc + bBase + (ni << 10) + cOff0);
        bb[ni][1] = *(const short8*)(Bc + bBase + (ni << 10) + cOff1);
    }
    if (t + 1 < nt) { stage512(An, Ag, K, kb1, 512, wv, lane); stage512(An, Ag, K, kb1, 1536, wv, lane); }
    phase_mid();
#pragma unroll
    for (int ml = 0; ml < 4; ++ml)
#pragma unroll
        for (int ni = 0; ni < 2; ++ni) {
            acc[ml][ni] = __builtin_amdgcn_mfma_f32_16x16x32_bf16(af[ml][0], bb[ni][0], acc[ml][ni], 0, 0, 0);
            acc[ml][ni] = __builtin_amdgcn_mfma_f32_16x16x32_bf16(af[ml][1], bb[ni][1], acc[ml][ni], 0, 0, 0);
        }
    phase_end();

    // ---- phase 2: ds_read B ni2-3 ; stage (t+2) A-part1 -> Ac (rows read in p1)
#pragma unroll
    for (int ni = 2; ni < 4; ++ni) {
        bb[ni][0] = *(const short8*)(Bc + bBase + (ni << 10) + cOff0);
        bb[ni][1] = *(const short8*)(Bc + bBase + (ni << 10) + cOff1);
    }
    if (t + 2 < nt) { stage512(Ac, Ag, K, kb2, 0, wv, lane); stage512(Ac, Ag, K, kb2, 1024, wv, lane); }
    phase_mid();
#pragma unroll
    for (int ml = 0; ml < 4; ++ml)
#pragma unroll
        for (int ni = 2; ni < 4; ++ni) {
            acc[ml][ni] = __builtin_amdgcn_mfma_f32_16x16x32_bf16(af[ml][0], bb[ni][0], acc[ml][ni], 0, 0, 0);
            acc[ml][ni] = __builtin_amdgcn_mfma_f32_16x16x32_bf16(af[ml][1], bb[ni][1], acc[ml][ni], 0, 0, 0);
        }
    phase_end();

    // ---- phase 3: ds_read A rows mi4-7 ; stage (t+2) B rows 0-127 (read p1/p2)
#pragma unroll
    for (int ml = 0; ml < 4; ++ml) {
        af[ml][0] = *(const short8*)(Ac + aBase + 4096 + (ml << 10) + cOff0);
        af[ml][1] = *(const short8*)(Ac + aBase + 4096 + (ml << 10) + cOff1);
    }
    if (t + 2 < nt) { stage512(Bc, Bg, K, kb2, 0, wv, lane); stage512(Bc, Bg, K, kb2, 512, wv, lane); }
    phase_mid();
#pragma unroll
    for (int ml = 0; ml < 4; ++ml)
#pragma unroll
        for (int ni = 0; ni < 2; ++ni) {
            acc[4 + ml][ni] = __builtin_amdgcn_mfma_f32_16x16x32_bf16(af[ml][0], bb[ni][0], acc[4 + ml][ni], 0, 0, 0);
            acc[4 + ml][ni] = __builtin_amdgcn_mfma_f32_16x16x32_bf16(af[ml][1], bb[ni][1], acc[4 + ml][ni], 0, 0, 0);
        }
    phase_end();

    // ---- phase 4: stage (t+2) B rows 128-255 ; counted vmcnt for tile t+1
    if (t + 2 < nt) { stage512(Bc, Bg, K, kb2, 1024, wv, lane); stage512(Bc, Bg, K, kb2, 1536, wv, lane); }
    __builtin_amdgcn_sched_barrier(0);
    if (t < nt - 2) asm volatile("s_waitcnt vmcnt(6)" ::: "memory");
    else            asm volatile("s_waitcnt vmcnt(0)" ::: "memory");
    __builtin_amdgcn_s_barrier();
    __builtin_amdgcn_sched_barrier(0);
    __builtin_amdgcn_s_setprio(1);
#pragma unroll
    for (int ml = 0; ml < 4; ++ml)
#pragma unroll
        for (int ni = 2; ni < 4; ++ni) {
            acc[4 + ml][ni] = __builtin_amdgcn_mfma_f32_16x16x32_bf16(af[ml][0], bb[ni][0], acc[4 + ml][ni], 0, 0, 0);
            acc[4 + ml][ni] = __builtin_amdgcn_mfma_f32_16x16x32_bf16(af[ml][1], bb[ni][1], acc[4 + ml][ni], 0, 0, 0);
        }
    phase_end();
}

__launch_bounds__(512, 2) __global__
void gemm_big256(const bf16* __restrict__ A, const bf16* __restrict__ Bt,
                 float* __restrict__ C, const int Nc, const int K)
{
    __shared__ __attribute__((aligned(16))) short smem[65536];   // 128 KiB (gfx950: 160 KiB addressable)
    short* A0s = smem;
    short* A1s = smem + 16384;
    short* B0s = smem + 32768;
    short* B1s = smem + 49152;

    const int nblkx = Nc >> 8;                 // 8
    const int bx = blockIdx.x % nblkx;
    const int by = blockIdx.x / nblkx;
    const int tid = threadIdx.x;
    const int lane = tid & 63;
    const int q = lane >> 4;
    const int l15 = lane & 15;
    const int wv = tid >> 6;                   // 0..7
    const int wm = wv >> 2;                    // 0..1 (row half)
    const int wn = wv & 3;                     // 0..3 (col quarter)

    const short* Ag = (const short*)A + (size_t)(by << 8) * K;
    const short* Bg = (const short*)Bt + (size_t)(bx << 8) * K;

    // ds_read offsets (shorts). row&7 == l15&7 for all fragment rows, so the
    // swizzled k-chunk is ((q + 4*kk) ^ (l15&7)).
    const int swz = l15 & 7;
    const int aBase = ((wm << 7) + l15) << 6;  // (wm*128 + l15) * 64
    const int bBase = ((wn << 6) + l15) << 6;  // (wn*64  + l15) * 64
    const int cOff0 = (q ^ swz) << 3;
    const int cOff1 = ((q + 4) ^ swz) << 3;

    floatx4 acc[8][4];
#pragma unroll
    for (int i = 0; i < 8; ++i)
#pragma unroll
        for (int j = 0; j < 4; ++j)
            acc[i][j] = (floatx4){0.f, 0.f, 0.f, 0.f};

    const int nt = K >> 6;                     // 32 K-tiles of 64

    // prologue: T0 full (8 loads) + T1 {A-part1, B-full} (6 loads); wait T0.
    stage512(A0s, Ag, K, 0, 0,    wv, lane);
    stage512(A0s, Ag, K, 0, 512,  wv, lane);
    stage512(A0s, Ag, K, 0, 1024, wv, lane);
    stage512(A0s, Ag, K, 0, 1536, wv, lane);
    stage512(B0s, Bg, K, 0, 0,    wv, lane);
    stage512(B0s, Bg, K, 0, 512,  wv, lane);
    stage512(B0s, Bg, K, 0, 1024, wv, lane);
    stage512(B0s, Bg, K, 0, 1536, wv, lane);
    stage512(A1s, Ag, K, 64, 0,    wv, lane);
    stage512(A1s, Ag, K, 64, 1024, wv, lane);
    stage512(B1s, Bg, K, 64, 0,    wv, lane);
    stage512(B1s, Bg, K, 64, 512,  wv, lane);
    stage512(B1s, Bg, K, 64, 1024, wv, lane);
    stage512(B1s, Bg, K, 64, 1536, wv, lane);
    __builtin_amdgcn_sched_barrier(0);
    asm volatile("s_waitcnt vmcnt(6)" ::: "memory");
    __builtin_amdgcn_s_barrier();

    for (int t = 0; t < nt; t += 2) {
        tile256(A0s, B0s, A1s, Ag, Bg, K, nt, t,     wv, lane, aBase, bBase, cOff0, cOff1, acc);
        tile256(A1s, B1s, A0s, Ag, Bg, K, nt, t + 1, wv, lane, aBase, bBase, cOff0, cOff1, acc);
    }

    // epilogue: C/D layout col = lane&15, row = quad*4 + reg (m89-verified)
#pragma unroll
    for (int mi = 0; mi < 8; ++mi)
#pragma unroll
        for (int ni = 0; ni < 4; ++ni)
#pragma unroll
            for (int r = 0; r < 4; ++r) {
                const int row = (by << 8) + (wm << 7) + (mi << 4) + (q << 2) + r;
                const int col = (bx << 8) + (wn << 6) + (ni << 4) + l15;
                C[(size_t)row * Nc + col] = acc[mi][ni][r];
            }
}

// ---------------- Tier-B (round-2 proven) manual-staging GEMM ----------------
template <int EPI, bool AF32, bool OF32>
__launch_bounds__(256, 2) __global__
void gemm_bt(const void* __restrict__ Ap, const bf16* __restrict__ Bt,
             void* __restrict__ Cp, const int Nc, const int K,
             const bf16* __restrict__ add1, const bf16* __restrict__ add2,
             const float* __restrict__ thetaP)
{
    __shared__ __attribute__((aligned(16))) short aT[128 * 32];
    __shared__ __attribute__((aligned(16))) short bT[128 * 32];

    const int nblk = Nc >> 7;
    const int bx = blockIdx.x % nblk;
    const int by = blockIdx.x / nblk;
    const int tid = threadIdx.x;
    const int lane = tid & 63;
    const int quad = lane >> 4;
    const int l15 = lane & 15;
    const int wv = tid >> 6;
    const int wr = (wv >> 1) << 6;
    const int wc = (wv & 1) << 6;

    const short* Ag = (const short*)Ap + (size_t)(by << 7) * K;
    const float* Agf = (const float*)Ap + (size_t)(by << 7) * K;
    const short* Bg = (const short*)Bt + (size_t)(bx << 7) * K;

    floatx4 acc[4][4];
#pragma unroll
    for (int i = 0; i < 4; ++i)
#pragma unroll
        for (int j = 0; j < 4; ++j)
            acc[i][j] = (floatx4){0.f, 0.f, 0.f, 0.f};

    for (int k0 = 0; k0 < K; k0 += 32) {
#pragma unroll
        for (int c = 0; c < 2; ++c) {
            const int ch = tid + (c << 8);
            const int row = ch >> 2;
            const int kp = (ch & 3) << 3;
            if (AF32) {
                const float4 f0 = *(const float4*)(Agf + (size_t)row * K + k0 + kp);
                const float4 f1 = *(const float4*)(Agf + (size_t)row * K + k0 + kp + 4);
                short8 pk;
                pk[0] = __builtin_bit_cast(short, __float2bfloat16(f0.x));
                pk[1] = __builtin_bit_cast(short, __float2bfloat16(f0.y));
                pk[2] = __builtin_bit_cast(short, __float2bfloat16(f0.z));
                pk[3] = __builtin_bit_cast(short, __float2bfloat16(f0.w));
                pk[4] = __builtin_bit_cast(short, __float2bfloat16(f1.x));
                pk[5] = __builtin_bit_cast(short, __float2bfloat16(f1.y));
                pk[6] = __builtin_bit_cast(short, __float2bfloat16(f1.z));
                pk[7] = __builtin_bit_cast(short, __float2bfloat16(f1.w));
                *(short8*)(aT + (row << 5) + kp) = pk;
            } else {
                *(int4*)(aT + (row << 5) + kp) = *(const int4*)(Ag + (size_t)row * K + k0 + kp);
            }
            *(int4*)(bT + (row << 5) + kp) = *(const int4*)(Bg + (size_t)row * K + k0 + kp);
        }
        __syncthreads();
        short8 af[4], bfr[4];
#pragma unroll
        for (int mi = 0; mi < 4; ++mi)
            af[mi] = *(const short8*)(aT + ((wr + (mi << 4) + l15) << 5) + (quad << 3));
#pragma unroll
        for (int ni = 0; ni < 4; ++ni)
            bfr[ni] = *(const short8*)(bT + ((wc + (ni << 4) + l15) << 5) + (quad << 3));
#pragma unroll
        for (int mi = 0; mi < 4; ++mi)
#pragma unroll
            for (int ni = 0; ni < 4; ++ni)
                acc[mi][ni] = __builtin_amdgcn_mfma_f32_16x16x32_bf16(af[mi], bfr[ni], acc[mi][ni], 0, 0, 0);
        __syncthreads();
    }

    float ct = 0.f, st = 0.f;
    if (EPI == EPI_P_ROT) {
        const float th = *thetaP;
        ct = cosf(th);
        st = sinf(th);
    }

#pragma unroll
    for (int mi = 0; mi < 4; ++mi) {
#pragma unroll
        for (int ni = 0; ni < 4; ++ni) {
#pragma unroll
            for (int r = 0; r < 4; ++r) {
                const int row = (by << 7) + wr + (mi << 4) + (quad << 2) + r;
                const int col = (bx << 7) + wc + (ni << 4) + l15;
                const size_t idx = (size_t)row * Nc + col;
                float v = acc[mi][ni][r];
                if (EPI == EPI_NEG) v = -v;
                if (EPI == EPI_ADD1) v += __bfloat162float(add1[idx]);
                if (EPI == EPI_P || EPI == EPI_P_ROT)
                    v += (row == col ? 1.f : 0.f)
                       + __bfloat162float(add1[idx]) + __bfloat162float(add2[idx]);
                if (EPI == EPI_P_ROT) {
                    const float w = __shfl_xor(v, 1, 64);
                    v = (l15 & 1) ? (st * w + ct * v) : (ct * v - st * w);
                }
                if (OF32) ((float*)Cp)[idx] = v;
                else      ((bf16*)Cp)[idx] = __float2bfloat16(v);
            }
        }
    }
}

// ---------------- launch ----------------
// out = x @ P1 @ R @ P2,  P = (I+M)^2 (I+M^2+M^4),  M = 0.5(W^T - W)
// Tier A (ws >= 6*ND^2*2 + tokens*ND*2 bytes): dual-batched chains + async GEMM + bf16 x;
//   final big GEMM now runs the 256^2/BK=64/8-phase counted-vmcnt kernel.
// Tier B: round-2 proven sequence (5 buffers, fp32 A staging on the big GEMM).

extern "C" void kernel_launch(void* const* d_in, const int* in_sizes, int n_in,
                              void* d_out, int out_size, void* d_ws, size_t ws_size,
                              hipStream_t stream)
{
    const float* x = (const float*)d_in[0];
    const float* u1 = (const float*)d_in[1];
    const float* u2 = (const float*)d_in[2];
    const float* th = (const float*)d_in[3];
    float* out = (float*)d_out;
    const int tokens = in_sizes[0] / ND;

    const size_t MAT = (size_t)ND * ND;
    const size_t XBE = (size_t)tokens * ND;

    const dim3 blk(256);
    const int gSkew = (ND / 32) * (ND / 32);
    const int gElem = (int)(MAT / 256);
    const int gSm = (ND / 128) * (ND / 128);        // 256
    const int gBig = (tokens / 128) * (ND / 128);   // 2048

    if (ws_size >= (6 * MAT + XBE) * sizeof(bf16)) {
        // ---------------- Tier A ----------------
        bf16* base = (bf16*)d_ws;
        bf16* b0 = base;            // M2 -> P2T
        bf16* b1 = base + MAT;      // M1 -> P1R
        bf16* b2 = base + 2 * MAT;  // Msq2 -> Hoff2 -> QT
        bf16* b3 = base + 3 * MAT;  // Msq1 -> Hoff1
        bf16* b4 = base + 4 * MAT;  // Goff2
        bf16* b5 = base + 5 * MAT;  // Goff1
        bf16* xb = base + 6 * MAT;  // x as bf16

        convert_f32_bf16<<<(int)(XBE / 2048), blk, 0, stream>>>(x, xb);
        build_skew<<<gSkew, blk, 0, stream>>>(u2, b0);   // M2
        build_skew<<<gSkew, blk, 0, stream>>>(u1, b1);   // M1
        // Msq = -(M @ M^T)  (M skew)
        gemm_dual<EPI_NEG, EPI_NEG><<<2 * gSm, blk, 0, stream>>>(
            b0, b0, b2, nullptr, nullptr,  b1, b1, b3, nullptr, nullptr, nullptr);
        // Goff = Msq@Msq + Msq   (Msq symmetric)
        gemm_dual<EPI_ADD1, EPI_ADD1><<<2 * gSm, blk, 0, stream>>>(
            b2, b2, b4, b2, nullptr,  b3, b3, b5, b3, nullptr, nullptr);
        // Hoff = 2M + Msq (in place over Msq)
        build_hoff1<<<gElem, blk, 0, stream>>>(b0, b2, b2);   // Hoff2
        build_hoff1<<<gElem, blk, 0, stream>>>(b1, b3, b3);   // Hoff1
        // P2T = I + Goff2 + Hoff2^T + Goff2@Hoff2^T  (PT: transposed add2)
        // P1R = (I + Goff1 + Hoff1 + Hoff1@Goff1) @ R
        gemm_dual<EPI_PT, EPI_P_ROT><<<2 * gSm, blk, 0, stream>>>(
            b4, b2, b0, b4, b2,  b3, b5, b1, b5, b3, th);
        // QT = P2T @ (P1R)^T
        gemm_one<EPI_PLAIN, false><<<gSm, blk, 0, stream>>>(b0, b1, b2, ND, ND, nullptr, nullptr, nullptr);
        // out = x @ QT^T  -- 256x256 8-phase kernel (fallback: old 128x128 path)
        if ((tokens & 255) == 0) {
            const int gBig256 = (tokens >> 8) * (ND >> 8);   // 512
            gemm_big256<<<gBig256, dim3(512), 0, stream>>>(xb, b2, out, ND, ND);
        } else {
            gemm_one<EPI_PLAIN, true><<<gBig, blk, 0, stream>>>(xb, b2, out, ND, ND, nullptr, nullptr, nullptr);
        }
    } else {
        // ---------------- Tier B (round-2 proven) ----------------
        bf16* A = (bf16*)d_ws;
        bf16* B = A + MAT;
        bf16* Cb = B + MAT;
        bf16* D = Cb + MAT;
        bf16* E = D + MAT;

        build_skew<<<gSkew, blk, 0, stream>>>(u2, A);
        gemm_bt<EPI_NEG, false, false><<<gSm, blk, 0, stream>>>(A, A, B, ND, ND, nullptr, nullptr, nullptr);
        gemm_bt<EPI_ADD1, false, false><<<gSm, blk, 0, stream>>>(B, B, Cb, ND, ND, B, nullptr, nullptr);
        build_hoff<<<gElem, blk, 0, stream>>>(A, B, D, E);
        gemm_bt<EPI_P, false, false><<<gSm, blk, 0, stream>>>(Cb, D, A, ND, ND, Cb, E, nullptr);

        build_skew<<<gSkew, blk, 0, stream>>>(u1, B);
        gemm_bt<EPI_NEG, false, false><<<gSm, blk, 0, stream>>>(B, B, Cb, ND, ND, nullptr, nullptr, nullptr);
        gemm_bt<EPI_ADD1, false, false><<<gSm, blk, 0, stream>>>(Cb, Cb, D, ND, ND, Cb, nullptr, nullptr);
        build_hoff<<<gElem, blk, 0, stream>>>(B, Cb, E, B);
        gemm_bt<EPI_P_ROT, false, false><<<gSm, blk, 0, stream>>>(E, D, Cb, ND, ND, D, E, th);

        gemm_bt<EPI_PLAIN, false, false><<<gSm, blk, 0, stream>>>(A, Cb, D, ND, ND, nullptr, nullptr, nullptr);
        gemm_bt<EPI_PLAIN, true, true><<<gBig, blk, 0, stream>>>(x, D, out, ND, ND, nullptr, nullptr, nullptr);
    }
}

// Round 2
// 584.329 us; speedup vs baseline: 1.0689x; 1.0244x over previous
//
#include <hip/hip_runtime.h>
#include <hip/hip_bf16.h>

#define ND 2048

using bf16 = __hip_bfloat16;
using short8 = __attribute__((ext_vector_type(8))) short;   // 8 bf16 = 4 VGPRs
using floatx4 = __attribute__((ext_vector_type(4))) float;

// ---------------- async global->LDS (16B per lane, wave-uniform LDS base) ----
__device__ __forceinline__ void gl2lds16(const short* g, short* l) {
    __builtin_amdgcn_global_load_lds(
        (const __attribute__((address_space(1))) unsigned int*)g,
        (__attribute__((address_space(3))) unsigned int*)l,
        16, 0, 0);
}

// chunked bijective XCD swizzle (requires grid % 8 == 0)
__device__ __forceinline__ int xcd_swz(int b, int g) {
    if ((g & 7) == 0) b = (b & 7) * (g >> 3) + (b >> 3);
    return b;
}

// ---------------- elementwise kernels ----------------

// M = 0.5*(u^T - u) (this is A.T of the reference), fp32 in -> bf16 out.
__global__ void build_skew(const float* __restrict__ u, bf16* __restrict__ M) {
    __shared__ float t[32][33];
    const int bx = blockIdx.x & (ND / 32 - 1);
    const int by = blockIdx.x / (ND / 32);
    const int tx = threadIdx.x & 31;
    const int ty = threadIdx.x >> 5;   // 0..7
#pragma unroll
    for (int rr = 0; rr < 4; ++rr) {
        const int r = ty * 4 + rr;
        t[tx][r] = u[(size_t)(bx * 32 + r) * ND + by * 32 + tx];
    }
    __syncthreads();
#pragma unroll
    for (int rr = 0; rr < 4; ++rr) {
        const int r = ty * 4 + rr;
        const size_t idx = (size_t)(by * 32 + r) * ND + bx * 32 + tx;
        M[idx] = __float2bfloat16(0.5f * (t[r][tx] - u[idx]));
    }
}

// Hoff = 2M + Msq (may alias Msq same-index -> no __restrict__ on those)
__global__ void build_hoff1(const bf16* __restrict__ M, const bf16* Msq, bf16* Hoff) {
    const size_t idx = (size_t)blockIdx.x * 256 + threadIdx.x;
    const float m = __bfloat162float(M[idx]);
    const float q = __bfloat162float(Msq[idx]);
    Hoff[idx] = __float2bfloat16(2.f * m + q);
}

// Tier-B variant: also emits HoffT = -2M + Msq (HoffT may alias M)
__global__ void build_hoff(const bf16* M, const bf16* Msq, bf16* Hoff, bf16* HoffT) {
    const size_t idx = (size_t)blockIdx.x * 256 + threadIdx.x;
    const float m = __bfloat162float(M[idx]);
    const float q = __bfloat162float(Msq[idx]);
    Hoff[idx] = __float2bfloat16(2.f * m + q);
    HoffT[idx] = __float2bfloat16(q - 2.f * m);
}

// x fp32 -> bf16, 8 elems/thread
__global__ void convert_f32_bf16(const float* __restrict__ x, bf16* __restrict__ y) {
    const size_t base = ((size_t)blockIdx.x * 256 + threadIdx.x) * 8;
    const float4 f0 = *(const float4*)(x + base);
    const float4 f1 = *(const float4*)(x + base + 4);
    short8 pk;
    pk[0] = __builtin_bit_cast(short, __float2bfloat16(f0.x));
    pk[1] = __builtin_bit_cast(short, __float2bfloat16(f0.y));
    pk[2] = __builtin_bit_cast(short, __float2bfloat16(f0.z));
    pk[3] = __builtin_bit_cast(short, __float2bfloat16(f0.w));
    pk[4] = __builtin_bit_cast(short, __float2bfloat16(f1.x));
    pk[5] = __builtin_bit_cast(short, __float2bfloat16(f1.y));
    pk[6] = __builtin_bit_cast(short, __float2bfloat16(f1.z));
    pk[7] = __builtin_bit_cast(short, __float2bfloat16(f1.w));
    *(short8*)((short*)y + base) = pk;
}

// ---------------- epilogue modes ----------------
enum { EPI_PLAIN = 0, EPI_NEG = 1, EPI_ADD1 = 2, EPI_P = 3, EPI_P_ROT = 4, EPI_PT = 5 };
// EPI_PT: C = acc + I + add1 + add2^T   (transposed add2 read, kills HoffT buffer)

// ---------------- async-staged GEMM core: C = A @ Bt^T ----------------
// 128x128 tile, BK=32, 256 threads, global_load_lds dwordx4 staging (m97 structure).
template <int EPI, bool OF32>
__device__ __forceinline__ void gemm_core(
    short* aT, short* bT,
    const bf16* __restrict__ A, const bf16* __restrict__ Bt, void* __restrict__ Cp,
    const int Nc, const int K, const int bx, const int by,
    const bf16* __restrict__ add1, const bf16* __restrict__ add2,
    const float* __restrict__ thetaP)
{
    const int tid = threadIdx.x;
    const int lane = tid & 63;
    const int quad = lane >> 4;
    const int l15 = lane & 15;
    const int wv = tid >> 6;
    const int wr = (wv >> 1) << 6;   // wave row offset: 0 or 64
    const int wc = (wv & 1) << 6;    // wave col offset: 0 or 64

    const short* Ag = (const short*)A + (size_t)(by << 7) * K;
    const short* Bg = (const short*)Bt + (size_t)(bx << 7) * K;

    floatx4 acc[4][4];
#pragma unroll
    for (int i = 0; i < 4; ++i)
#pragma unroll
        for (int j = 0; j < 4; ++j)
            acc[i][j] = (floatx4){0.f, 0.f, 0.f, 0.f};

    for (int k0 = 0; k0 < K; k0 += 32) {
        // 128x32 tiles = 512 x 16B chunks each; 2 chunks/thread, async DMA.
        // chunk ch -> LDS shorts [ch*8, ch*8+8) ; wave-uniform base + lane*16B.
#pragma unroll
        for (int c = 0; c < 2; ++c) {
            const int ch = (c << 8) + (wv << 6) + lane;
            const int row = ch >> 2;
            const int kp = (ch & 3) << 3;                 // short offset in row
            const int ldsBase = ((c << 8) + (wv << 6)) << 3;  // shorts, wave-uniform
            gl2lds16(Ag + (size_t)row * K + k0 + kp, aT + ldsBase);
            gl2lds16(Bg + (size_t)row * K + k0 + kp, bT + ldsBase);
        }
        __syncthreads();
        short8 af[4], bfr[4];
#pragma unroll
        for (int mi = 0; mi < 4; ++mi)
            af[mi] = *(const short8*)(aT + ((wr + (mi << 4) + l15) << 5) + (quad << 3));
#pragma unroll
        for (int ni = 0; ni < 4; ++ni)
            bfr[ni] = *(const short8*)(bT + ((wc + (ni << 4) + l15) << 5) + (quad << 3));
#pragma unroll
        for (int mi = 0; mi < 4; ++mi)
#pragma unroll
            for (int ni = 0; ni < 4; ++ni)
                acc[mi][ni] = __builtin_amdgcn_mfma_f32_16x16x32_bf16(af[mi], bfr[ni], acc[mi][ni], 0, 0, 0);
        __syncthreads();
    }

    float ct = 0.f, st = 0.f;
    if (EPI == EPI_P_ROT) {
        const float th = *thetaP;
        ct = cosf(th);
        st = sinf(th);
    }

    // C/D layout (m89-verified): col = lane&15, row = quad*4 + reg
#pragma unroll
    for (int mi = 0; mi < 4; ++mi) {
#pragma unroll
        for (int ni = 0; ni < 4; ++ni) {
#pragma unroll
            for (int r = 0; r < 4; ++r) {
                const int row = (by << 7) + wr + (mi << 4) + (quad << 2) + r;
                const int col = (bx << 7) + wc + (ni << 4) + l15;
                const size_t idx = (size_t)row * Nc + col;
                float v = acc[mi][ni][r];
                if (EPI == EPI_NEG) v = -v;
                if (EPI == EPI_ADD1) v += __bfloat162float(add1[idx]);
                if (EPI == EPI_P)
                    v += (row == col ? 1.f : 0.f)
                       + __bfloat162float(add1[idx]) + __bfloat162float(add2[idx]);
                if (EPI == EPI_PT)
                    v += (row == col ? 1.f : 0.f)
                       + __bfloat162float(add1[idx])
                       + __bfloat162float(add2[(size_t)col * Nc + row]);
                if (EPI == EPI_P_ROT) {
                    v += (row == col ? 1.f : 0.f)
                       + __bfloat162float(add1[idx]) + __bfloat162float(add2[idx]);
                    const float w = __shfl_xor(v, 1, 64);
                    v = (l15 & 1) ? (st * w + ct * v) : (ct * v - st * w);
                }
                if (OF32) ((float*)Cp)[idx] = v;
                else      ((bf16*)Cp)[idx] = __float2bfloat16(v);
            }
        }
    }
}

template <int EPI, bool OF32>
__launch_bounds__(256, 2) __global__
void gemm_one(const bf16* __restrict__ A, const bf16* __restrict__ Bt,
              void* __restrict__ Cp, const int Nc, const int K,
              const bf16* __restrict__ add1, const bf16* __restrict__ add2,
              const float* __restrict__ thetaP)
{
    __shared__ __attribute__((aligned(16))) short aT[128 * 32];
    __shared__ __attribute__((aligned(16))) short bT[128 * 32];
    const int nblk = Nc >> 7;
    const int b = xcd_swz(blockIdx.x, gridDim.x);
    gemm_core<EPI, OF32>(aT, bT, A, Bt, Cp, Nc, K, b % nblk, b / nblk,
                         add1, add2, thetaP);
}

// Two independent 2048^2 GEMMs in one dispatch (grid = 512 -> 2 blocks/CU).
template <int EPI0, int EPI1>
__launch_bounds__(256, 2) __global__
void gemm_dual(const bf16* A0, const bf16* B0, bf16* C0, const bf16* a10, const bf16* a20,
               const bf16* A1, const bf16* B1, bf16* C1, const bf16* a11, const bf16* a21,
               const float* thetaP)
{
    __shared__ __attribute__((aligned(16))) short aT[128 * 32];
    __shared__ __attribute__((aligned(16))) short bT[128 * 32];
    const int nblk = ND >> 7;          // 16
    const int nsub = nblk * nblk;      // 256
    int b = xcd_swz(blockIdx.x, gridDim.x);
    if (b < nsub) {
        gemm_core<EPI0, false>(aT, bT, A0, B0, (void*)C0, ND, ND, b % nblk, b / nblk, a10, a20, thetaP);
    } else {
        b -= nsub;
        gemm_core<EPI1, false>(aT, bT, A1, B1, (void*)C1, ND, ND, b % nblk, b / nblk, a11, a21, thetaP);
    }
}

// ================== 256x256 / BK=64 / 8-phase / counted-vmcnt big GEMM =======
// C(fp32)[M][Nc] = A(bf16)[M][K] @ Bt(bf16)[Nc][K]^T
// 512 threads = 8 waves (2M x 4N); per-wave 128x64 output; LDS 128 KiB static.
// R2: register-fragment software pipeline — each phase's ds_reads are issued one
// phase EARLY so the LDS burst is serviced UNDER the previous phase's MFMA
// cluster.  Counted lgkmcnt per phase; counted vmcnt moves to P2/P3/P4.
// Operand load schedule (steady state, tile t):
//   afLo(t) <- issued P3(t-1);  bb01(t) <- issued P4(t-1)
//   bb23(t) <- issued P1(t);    afHi(t) <- issued P1(t)
// Staging (unchanged): P1: A2(t+1)->An; P2: A1(t+2)->Ac; P3: Blo(t+2)->Bc;
//   P4: Bhi(t+2)->Bc.  vmcnt(8)@P2 guarantees A-low(t+1) before P3's reads;
//   vmcnt(6)@P3 guarantees B(t+1) before P4's reads; vmcnt(6)@P4 guarantees
//   A-hi(t+1) before P1(t+1)'s reads.  Never vmcnt(0) until the last 2 tiles.

__device__ __forceinline__ void stage512(short* ldsT, const short* gT, const int K,
                                         const int kb, const int c0,
                                         const int wv, const int lane) {
    const int ch = c0 + (wv << 6) + lane;      // chunk index in 256x64 tile
    const int rw = ch >> 3;                    // row (8 chunks of 16B per row)
    const int cs = (ch & 7) ^ (rw & 7);        // inverse-swizzled source k-chunk
    gl2lds16(gT + (size_t)rw * K + kb + (cs << 3),
             ldsT + ((c0 + (wv << 6)) << 3));  // wave-uniform linear LDS dest
}

__device__ __forceinline__ void phase_end() {
    __builtin_amdgcn_s_setprio(0);
    __builtin_amdgcn_sched_barrier(0);
    __builtin_amdgcn_s_barrier();
}

#define MFMA_BF16 __builtin_amdgcn_mfma_f32_16x16x32_bf16

__device__ __forceinline__ void tile256p(
    short* Ac, short* Bc, short* An, short* Bn,
    const short* Ag, const short* Bg, const int K, const int nt, const int t,
    const int wv, const int lane, const int aBase, const int bBase,
    const int cOff0, const int cOff1,
    short8 (&afLo)[4][2], short8 (&afHi)[4][2], short8 (&bb)[4][2],
    floatx4 (&acc)[8][4])
{
    const int kb1 = (t + 1) << 6;
    const int kb2 = (t + 2) << 6;
    const bool sfull = (t < nt - 2);

    // ---- P1: issue bb23(t) [oldest], afHi(t); stage A2(t+1); MFMA Lo x B01
#pragma unroll
    for (int ni = 2; ni < 4; ++ni) {
        bb[ni][0] = *(const short8*)(Bc + bBase + (ni << 10) + cOff0);
        bb[ni][1] = *(const short8*)(Bc + bBase + (ni << 10) + cOff1);
    }
#pragma unroll
    for (int ml = 0; ml < 4; ++ml) {
        afHi[ml][0] = *(const short8*)(Ac + aBase + 4096 + (ml << 10) + cOff0);
        afHi[ml][1] = *(const short8*)(Ac + aBase + 4096 + (ml << 10) + cOff1);
    }
    if (t + 1 < nt) { stage512(An, Ag, K, kb1, 512, wv, lane); stage512(An, Ag, K, kb1, 1536, wv, lane); }
    __builtin_amdgcn_sched_barrier(0);
    __builtin_amdgcn_s_barrier();
    asm volatile("s_waitcnt lgkmcnt(12)" ::: "memory");   // afLo(t), bb01(t) ready
    __builtin_amdgcn_sched_barrier(0);
    __builtin_amdgcn_s_setprio(1);
#pragma unroll
    for (int ml = 0; ml < 4; ++ml)
#pragma unroll
        for (int ni = 0; ni < 2; ++ni) {
            acc[ml][ni] = MFMA_BF16(afLo[ml][0], bb[ni][0], acc[ml][ni], 0, 0, 0);
            acc[ml][ni] = MFMA_BF16(afLo[ml][1], bb[ni][1], acc[ml][ni], 0, 0, 0);
        }
    phase_end();

    // ---- P2: stage A1(t+2); vmcnt(8) [A-low(t+1) resident]; MFMA Lo x B23
    if (t + 2 < nt) { stage512(Ac, Ag, K, kb2, 0, wv, lane); stage512(Ac, Ag, K, kb2, 1024, wv, lane); }
    __builtin_amdgcn_sched_barrier(0);
    if (sfull) asm volatile("s_waitcnt vmcnt(8)" ::: "memory");
    else       asm volatile("s_waitcnt vmcnt(0)" ::: "memory");
    __builtin_amdgcn_s_barrier();
    asm volatile("s_waitcnt lgkmcnt(8)" ::: "memory");    // bb23(t) ready (oldest 4)
    __builtin_amdgcn_sched_barrier(0);
    __builtin_amdgcn_s_setprio(1);
#pragma unroll
    for (int ml = 0; ml < 4; ++ml)
#pragma unroll
        for (int ni = 2; ni < 4; ++ni) {
            acc[ml][ni] = MFMA_BF16(afLo[ml][0], bb[ni][0], acc[ml][ni], 0, 0, 0);
            acc[ml][ni] = MFMA_BF16(afLo[ml][1], bb[ni][1], acc[ml][ni], 0, 0, 0);
        }
    phase_end();

    // ---- P3: issue afLo(t+1); stage Blo(t+2); vmcnt(6) [B(t+1) resident];
    //          MFMA Hi x B01
    if (t + 1 < nt) {
#pragma unroll
        for (int ml = 0; ml < 4; ++ml) {
            afLo[ml][0] = *(const short8*)(An + aBase + (ml << 10) + cOff0);
            afLo[ml][1] = *(const short8*)(An + aBase + (ml << 10) + cOff1);
        }
    }
    if (t + 2 < nt) { stage512(Bc, Bg, K, kb2, 0, wv, lane); stage512(Bc, Bg, K, kb2, 512, wv, lane); }
    __builtin_amdgcn_sched_barrier(0);
    if (sfull) asm volatile("s_waitcnt vmcnt(6)" ::: "memory");
    else       asm volatile("s_waitcnt vmcnt(0)" ::: "memory");
    __builtin_amdgcn_s_barrier();
    if (t + 1 < nt) asm volatile("s_waitcnt lgkmcnt(8)" ::: "memory");  // afHi(t) ready
    else            asm volatile("s_waitcnt lgkmcnt(0)" ::: "memory");
    __builtin_amdgcn_sched_barrier(0);
    __builtin_amdgcn_s_setprio(1);
#pragma unroll
    for (int ml = 0; ml < 4; ++ml)
#pragma unroll
        for (int ni = 0; ni < 2; ++ni) {
            acc[4 + ml][ni] = MFMA_BF16(afHi[ml][0], bb[ni][0], acc[4 + ml][ni], 0, 0, 0);
            acc[4 + ml][ni] = MFMA_BF16(afHi[ml][1], bb[ni][1], acc[4 + ml][ni], 0, 0, 0);
        }
    phase_end();

    // ---- P4: issue bb01(t+1); stage Bhi(t+2); vmcnt(6) [A-hi(t+1) resident];
    //          MFMA Hi x B23 (operands already in regs; no lgkm wait)
    if (t + 1 < nt) {
#pragma unroll
        for (int ni = 0; ni < 2; ++ni) {
            bb[ni][0] = *(const short8*)(Bn + bBase + (ni << 10) + cOff0);
            bb[ni][1] = *(const short8*)(Bn + bBase + (ni << 10) + cOff1);
        }
    }
    if (t + 2 < nt) { stage512(Bc, Bg, K, kb2, 1024, wv, lane); stage512(Bc, Bg, K, kb2, 1536, wv, lane); }
    __builtin_amdgcn_sched_barrier(0);
    if (sfull) asm volatile("s_waitcnt vmcnt(6)" ::: "memory");
    else       asm volatile("s_waitcnt vmcnt(0)" ::: "memory");
    __builtin_amdgcn_s_barrier();
    __builtin_amdgcn_sched_barrier(0);
    __builtin_amdgcn_s_setprio(1);
#pragma unroll
    for (int ml = 0; ml < 4; ++ml)
#pragma unroll
        for (int ni = 2; ni < 4; ++ni) {
            acc[4 + ml][ni] = MFMA_BF16(afHi[ml][0], bb[ni][0], acc[4 + ml][ni], 0, 0, 0);
            acc[4 + ml][ni] = MFMA_BF16(afHi[ml][1], bb[ni][1], acc[4 + ml][ni], 0, 0, 0);
        }
    phase_end();
}

__launch_bounds__(512, 2) __global__
void gemm_big256(const bf16* __restrict__ A, const bf16* __restrict__ Bt,
                 float* __restrict__ C, const int Nc, const int K)
{
    __shared__ __attribute__((aligned(16))) short smem[65536];   // 128 KiB
    short* A0s = smem;
    short* A1s = smem + 16384;
    short* B0s = smem + 32768;
    short* B1s = smem + 49152;

    const int nblkx = Nc >> 8;                 // 8
    const int b = xcd_swz(blockIdx.x, gridDim.x);
    const int bx = b % nblkx;
    const int by = b / nblkx;
    const int tid = threadIdx.x;
    const int lane = tid & 63;
    const int q = lane >> 4;
    const int l15 = lane & 15;
    const int wv = tid >> 6;                   // 0..7
    const int wm = wv >> 2;                    // 0..1 (row half)
    const int wn = wv & 3;                     // 0..3 (col quarter)

    const short* Ag = (const short*)A + (size_t)(by << 8) * K;
    const short* Bg = (const short*)Bt + (size_t)(bx << 8) * K;

    // ds_read offsets (shorts). row&7 == l15&7 for all fragment rows, so the
    // swizzled k-chunk is ((q + 4*kk) ^ (l15&7)).
    const int swz = l15 & 7;
    const int aBase = ((wm << 7) + l15) << 6;  // (wm*128 + l15) * 64
    const int bBase = ((wn << 6) + l15) << 6;  // (wn*64  + l15) * 64
    const int cOff0 = (q ^ swz) << 3;
    const int cOff1 = ((q + 4) ^ swz) << 3;

    floatx4 acc[8][4];
#pragma unroll
    for (int i = 0; i < 8; ++i)
#pragma unroll
        for (int j = 0; j < 4; ++j)
            acc[i][j] = (floatx4){0.f, 0.f, 0.f, 0.f};

    short8 afLo[4][2], afHi[4][2], bb[4][2];

    const int nt = K >> 6;                     // 32 K-tiles of 64

    // prologue: T0 full (8 loads) + T1 {A-part1, B-full} (6 loads); wait T0.
    stage512(A0s, Ag, K, 0, 0,    wv, lane);
    stage512(A0s, Ag, K, 0, 512,  wv, lane);
    stage512(A0s, Ag, K, 0, 1024, wv, lane);
    stage512(A0s, Ag, K, 0, 1536, wv, lane);
    stage512(B0s, Bg, K, 0, 0,    wv, lane);
    stage512(B0s, Bg, K, 0, 512,  wv, lane);
    stage512(B0s, Bg, K, 0, 1024, wv, lane);
    stage512(B0s, Bg, K, 0, 1536, wv, lane);
    stage512(A1s, Ag, K, 64, 0,    wv, lane);
    stage512(A1s, Ag, K, 64, 1024, wv, lane);
    stage512(B1s, Bg, K, 64, 0,    wv, lane);
    stage512(B1s, Bg, K, 64, 512,  wv, lane);
    stage512(B1s, Bg, K, 64, 1024, wv, lane);
    stage512(B1s, Bg, K, 64, 1536, wv, lane);
    __builtin_amdgcn_sched_barrier(0);
    asm volatile("s_waitcnt vmcnt(6)" ::: "memory");   // T0 resident
    __builtin_amdgcn_s_barrier();
    __builtin_amdgcn_sched_barrier(0);
    // pre-issue afLo(0), bb01(0)
#pragma unroll
    for (int ml = 0; ml < 4; ++ml) {
        afLo[ml][0] = *(const short8*)(A0s + aBase + (ml << 10) + cOff0);
        afLo[ml][1] = *(const short8*)(A0s + aBase + (ml << 10) + cOff1);
    }
#pragma unroll
    for (int ni = 0; ni < 2; ++ni) {
        bb[ni][0] = *(const short8*)(B0s + bBase + (ni << 10) + cOff0);
        bb[ni][1] = *(const short8*)(B0s + bBase + (ni << 10) + cOff1);
    }
    __builtin_amdgcn_sched_barrier(0);

    for (int t = 0; t < nt; t += 2) {
        tile256p(A0s, B0s, A1s, B1s, Ag, Bg, K, nt, t,
                 wv, lane, aBase, bBase, cOff0, cOff1, afLo, afHi, bb, acc);
        tile256p(A1s, B1s, A0s, B0s, Ag, Bg, K, nt, t + 1,
                 wv, lane, aBase, bBase, cOff0, cOff1, afLo, afHi, bb, acc);
    }

    // epilogue: C/D layout col = lane&15, row = quad*4 + reg (m89-verified)
#pragma unroll
    for (int mi = 0; mi < 8; ++mi)
#pragma unroll
        for (int ni = 0; ni < 4; ++ni)
#pragma unroll
            for (int r = 0; r < 4; ++r) {
                const int row = (by << 8) + (wm << 7) + (mi << 4) + (q << 2) + r;
                const int col = (bx << 8) + (wn << 6) + (ni << 4) + l15;
                C[(size_t)row * Nc + col] = acc[mi][ni][r];
            }
}

// ---------------- Tier-B (round-2 proven) manual-staging GEMM ----------------
template <int EPI, bool AF32, bool OF32>
__launch_bounds__(256, 2) __global__
void gemm_bt(const void* __restrict__ Ap, const bf16* __restrict__ Bt,
             void* __restrict__ Cp, const int Nc, const int K,
             const bf16* __restrict__ add1, const bf16* __restrict__ add2,
             const float* __restrict__ thetaP)
{
    __shared__ __attribute__((aligned(16))) short aT[128 * 32];
    __shared__ __attribute__((aligned(16))) short bT[128 * 32];

    const int nblk = Nc >> 7;
    const int bx = blockIdx.x % nblk;
    const int by = blockIdx.x / nblk;
    const int tid = threadIdx.x;
    const int lane = tid & 63;
    const int quad = lane >> 4;
    const int l15 = lane & 15;
    const int wv = tid >> 6;
    const int wr = (wv >> 1) << 6;
    const int wc = (wv & 1) << 6;

    const short* Ag = (const short*)Ap + (size_t)(by << 7) * K;
    const float* Agf = (const float*)Ap + (size_t)(by << 7) * K;
    const short* Bg = (const short*)Bt + (size_t)(bx << 7) * K;

    floatx4 acc[4][4];
#pragma unroll
    for (int i = 0; i < 4; ++i)
#pragma unroll
        for (int j = 0; j < 4; ++j)
            acc[i][j] = (floatx4){0.f, 0.f, 0.f, 0.f};

    for (int k0 = 0; k0 < K; k0 += 32) {
#pragma unroll
        for (int c = 0; c < 2; ++c) {
            const int ch = tid + (c << 8);
            const int row = ch >> 2;
            const int kp = (ch & 3) << 3;
            if (AF32) {
                const float4 f0 = *(const float4*)(Agf + (size_t)row * K + k0 + kp);
                const float4 f1 = *(const float4*)(Agf + (size_t)row * K + k0 + kp + 4);
                short8 pk;
                pk[0] = __builtin_bit_cast(short, __float2bfloat16(f0.x));
                pk[1] = __builtin_bit_cast(short, __float2bfloat16(f0.y));
                pk[2] = __builtin_bit_cast(short, __float2bfloat16(f0.z));
                pk[3] = __builtin_bit_cast(short, __float2bfloat16(f0.w));
                pk[4] = __builtin_bit_cast(short, __float2bfloat16(f1.x));
                pk[5] = __builtin_bit_cast(short, __float2bfloat16(f1.y));
                pk[6] = __builtin_bit_cast(short, __float2bfloat16(f1.z));
                pk[7] = __builtin_bit_cast(short, __float2bfloat16(f1.w));
                *(short8*)(aT + (row << 5) + kp) = pk;
            } else {
                *(int4*)(aT + (row << 5) + kp) = *(const int4*)(Ag + (size_t)row * K + k0 + kp);
            }
            *(int4*)(bT + (row << 5) + kp) = *(const int4*)(Bg + (size_t)row * K + k0 + kp);
        }
        __syncthreads();
        short8 af[4], bfr[4];
#pragma unroll
        for (int mi = 0; mi < 4; ++mi)
            af[mi] = *(const short8*)(aT + ((wr + (mi << 4) + l15) << 5) + (quad << 3));
#pragma unroll
        for (int ni = 0; ni < 4; ++ni)
            bfr[ni] = *(const short8*)(bT + ((wc + (ni << 4) + l15) << 5) + (quad << 3));
#pragma unroll
        for (int mi = 0; mi < 4; ++mi)
#pragma unroll
            for (int ni = 0; ni < 4; ++ni)
                acc[mi][ni] = __builtin_amdgcn_mfma_f32_16x16x32_bf16(af[mi], bfr[ni], acc[mi][ni], 0, 0, 0);
        __syncthreads();
    }

    float ct = 0.f, st = 0.f;
    if (EPI == EPI_P_ROT) {
        const float th = *thetaP;
        ct = cosf(th);
        st = sinf(th);
    }

#pragma unroll
    for (int mi = 0; mi < 4; ++mi) {
#pragma unroll
        for (int ni = 0; ni < 4; ++ni) {
#pragma unroll
            for (int r = 0; r < 4; ++r) {
                const int row = (by << 7) + wr + (mi << 4) + (quad << 2) + r;
                const int col = (bx << 7) + wc + (ni << 4) + l15;
                const size_t idx = (size_t)row * Nc + col;
                float v = acc[mi][ni][r];
                if (EPI == EPI_NEG) v = -v;
                if (EPI == EPI_ADD1) v += __bfloat162float(add1[idx]);
                if (EPI == EPI_P || EPI == EPI_P_ROT)
                    v += (row == col ? 1.f : 0.f)
                       + __bfloat162float(add1[idx]) + __bfloat162float(add2[idx]);
                if (EPI == EPI_P_ROT) {
                    const float w = __shfl_xor(v, 1, 64);
                    v = (l15 & 1) ? (st * w + ct * v) : (ct * v - st * w);
                }
                if (OF32) ((float*)Cp)[idx] = v;
                else      ((bf16*)Cp)[idx] = __float2bfloat16(v);
            }
        }
    }
}

// ---------------- launch ----------------
// out = x @ P1 @ R @ P2,  P = (I+M)^2 (I+M^2+M^4),  M = 0.5(W^T - W)
// Tier A (ws >= 6*ND^2*2 + tokens*ND*2 bytes): dual-batched chains + async GEMM + bf16 x;
//   final big GEMM: 256^2/BK=64/8-phase, register-pipelined, counted vmcnt/lgkm.
// Tier B: round-2 proven sequence (5 buffers, fp32 A staging on the big GEMM).

extern "C" void kernel_launch(void* const* d_in, const int* in_sizes, int n_in,
                              void* d_out, int out_size, void* d_ws, size_t ws_size,
                              hipStream_t stream)
{
    const float* x = (const float*)d_in[0];
    const float* u1 = (const float*)d_in[1];
    const float* u2 = (const float*)d_in[2];
    const float* th = (const float*)d_in[3];
    float* out = (float*)d_out;
    const int tokens = in_sizes[0] / ND;

    const size_t MAT = (size_t)ND * ND;
    const size_t XBE = (size_t)tokens * ND;

    const dim3 blk(256);
    const int gSkew = (ND / 32) * (ND / 32);
    const int gElem = (int)(MAT / 256);
    const int gSm = (ND / 128) * (ND / 128);        // 256
    const int gBig = (tokens / 128) * (ND / 128);   // 2048

    if (ws_size >= (6 * MAT + XBE) * sizeof(bf16)) {
        // ---------------- Tier A ----------------
        bf16* base = (bf16*)d_ws;
        bf16* b0 = base;            // M2 -> P2T
        bf16* b1 = base + MAT;      // M1 -> P1R
        bf16* b2 = base + 2 * MAT;  // Msq2 -> Hoff2 -> QT
        bf16* b3 = base + 3 * MAT;  // Msq1 -> Hoff1
        bf16* b4 = base + 4 * MAT;  // Goff2
        bf16* b5 = base + 5 * MAT;  // Goff1
        bf16* xb = base + 6 * MAT;  // x as bf16

        convert_f32_bf16<<<(int)(XBE / 2048), blk, 0, stream>>>(x, xb);
        build_skew<<<gSkew, blk, 0, stream>>>(u2, b0);   // M2
        build_skew<<<gSkew, blk, 0, stream>>>(u1, b1);   // M1
        // Msq = -(M @ M^T)  (M skew)
        gemm_dual<EPI_NEG, EPI_NEG><<<2 * gSm, blk, 0, stream>>>(
            b0, b0, b2, nullptr, nullptr,  b1, b1, b3, nullptr, nullptr, nullptr);
        // Goff = Msq@Msq + Msq   (Msq symmetric)
        gemm_dual<EPI_ADD1, EPI_ADD1><<<2 * gSm, blk, 0, stream>>>(
            b2, b2, b4, b2, nullptr,  b3, b3, b5, b3, nullptr, nullptr);
        // Hoff = 2M + Msq (in place over Msq)
        build_hoff1<<<gElem, blk, 0, stream>>>(b0, b2, b2);   // Hoff2
        build_hoff1<<<gElem, blk, 0, stream>>>(b1, b3, b3);   // Hoff1
        // P2T = I + Goff2 + Hoff2^T + Goff2@Hoff2^T  (PT: transposed add2)
        // P1R = (I + Goff1 + Hoff1 + Hoff1@Goff1) @ R
        gemm_dual<EPI_PT, EPI_P_ROT><<<2 * gSm, blk, 0, stream>>>(
            b4, b2, b0, b4, b2,  b3, b5, b1, b5, b3, th);
        // QT = P2T @ (P1R)^T
        gemm_one<EPI_PLAIN, false><<<gSm, blk, 0, stream>>>(b0, b1, b2, ND, ND, nullptr, nullptr, nullptr);
        // out = x @ QT^T  -- 256x256 8-phase pipelined kernel (fallback: 128x128)
        if ((tokens & 255) == 0) {
            const int gBig256 = (tokens >> 8) * (ND >> 8);   // 512
            gemm_big256<<<gBig256, dim3(512), 0, stream>>>(xb, b2, out, ND, ND);
        } else {
            gemm_one<EPI_PLAIN, true><<<gBig, blk, 0, stream>>>(xb, b2, out, ND, ND, nullptr, nullptr, nullptr);
        }
    } else {
        // ---------------- Tier B (round-2 proven) ----------------
        bf16* A = (bf16*)d_ws;
        bf16* B = A + MAT;
        bf16* Cb = B + MAT;
        bf16* D = Cb + MAT;
        bf16* E = D + MAT;

        build_skew<<<gSkew, blk, 0, stream>>>(u2, A);
        gemm_bt<EPI_NEG, false, false><<<gSm, blk, 0, stream>>>(A, A, B, ND, ND, nullptr, nullptr, nullptr);
        gemm_bt<EPI_ADD1, false, false><<<gSm, blk, 0, stream>>>(B, B, Cb, ND, ND, B, nullptr, nullptr);
        build_hoff<<<gElem, blk, 0, stream>>>(A, B, D, E);
        gemm_bt<EPI_P, false, false><<<gSm, blk, 0, stream>>>(Cb, D, A, ND, ND, Cb, E, nullptr);

        build_skew<<<gSkew, blk, 0, stream>>>(u1, B);
        gemm_bt<EPI_NEG, false, false><<<gSm, blk, 0, stream>>>(B, B, Cb, ND, ND, nullptr, nullptr, nullptr);
        gemm_bt<EPI_ADD1, false, false><<<gSm, blk, 0, stream>>>(Cb, Cb, D, ND, ND, Cb, nullptr, nullptr);
        build_hoff<<<gElem, blk, 0, stream>>>(B, Cb, E, B);
        gemm_bt<EPI_P_ROT, false, false><<<gSm, blk, 0, stream>>>(E, D, Cb, ND, ND, D, E, th);

        gemm_bt<EPI_PLAIN, false, false><<<gSm, blk, 0, stream>>>(A, Cb, D, ND, ND, nullptr, nullptr, nullptr);
        gemm_bt<EPI_PLAIN, true, true><<<gBig, blk, 0, stream>>>(x, D, out, ND, ND, nullptr, nullptr, nullptr);
    }
}

// Round 3
// 571.638 us; speedup vs baseline: 1.0926x; 1.0222x over previous
//
#include <hip/hip_runtime.h>
#include <hip/hip_bf16.h>

#define ND 2048

using bf16 = __hip_bfloat16;
using short8 = __attribute__((ext_vector_type(8))) short;   // 8 bf16 = 4 VGPRs
using floatx4 = __attribute__((ext_vector_type(4))) float;

// ---------------- async global->LDS (16B per lane, wave-uniform LDS base) ----
__device__ __forceinline__ void gl2lds16(const short* g, short* l) {
    __builtin_amdgcn_global_load_lds(
        (const __attribute__((address_space(1))) unsigned int*)g,
        (__attribute__((address_space(3))) unsigned int*)l,
        16, 0, 0);
}

// chunked bijective XCD swizzle (requires grid % 8 == 0)
__device__ __forceinline__ int xcd_swz(int b, int g) {
    if ((g & 7) == 0) b = (b & 7) * (g >> 3) + (b >> 3);
    return b;
}

// ---------------- elementwise kernels ----------------

// M = 0.5*(u^T - u) (this is A.T of the reference), fp32 in -> bf16 out.
__global__ void build_skew(const float* __restrict__ u, bf16* __restrict__ M) {
    __shared__ float t[32][33];
    const int bx = blockIdx.x & (ND / 32 - 1);
    const int by = blockIdx.x / (ND / 32);
    const int tx = threadIdx.x & 31;
    const int ty = threadIdx.x >> 5;   // 0..7
#pragma unroll
    for (int rr = 0; rr < 4; ++rr) {
        const int r = ty * 4 + rr;
        t[tx][r] = u[(size_t)(bx * 32 + r) * ND + by * 32 + tx];
    }
    __syncthreads();
#pragma unroll
    for (int rr = 0; rr < 4; ++rr) {
        const int r = ty * 4 + rr;
        const size_t idx = (size_t)(by * 32 + r) * ND + bx * 32 + tx;
        M[idx] = __float2bfloat16(0.5f * (t[r][tx] - u[idx]));
    }
}

// Hoff = 2M + Msq (may alias Msq same-index -> no __restrict__ on those)
__global__ void build_hoff1(const bf16* __restrict__ M, const bf16* Msq, bf16* Hoff) {
    const size_t idx = (size_t)blockIdx.x * 256 + threadIdx.x;
    const float m = __bfloat162float(M[idx]);
    const float q = __bfloat162float(Msq[idx]);
    Hoff[idx] = __float2bfloat16(2.f * m + q);
}

// Tier-B variant: also emits HoffT = -2M + Msq (HoffT may alias M)
__global__ void build_hoff(const bf16* M, const bf16* Msq, bf16* Hoff, bf16* HoffT) {
    const size_t idx = (size_t)blockIdx.x * 256 + threadIdx.x;
    const float m = __bfloat162float(M[idx]);
    const float q = __bfloat162float(Msq[idx]);
    Hoff[idx] = __float2bfloat16(2.f * m + q);
    HoffT[idx] = __float2bfloat16(q - 2.f * m);
}

// x fp32 -> bf16, 8 elems/thread
__global__ void convert_f32_bf16(const float* __restrict__ x, bf16* __restrict__ y) {
    const size_t base = ((size_t)blockIdx.x * 256 + threadIdx.x) * 8;
    const float4 f0 = *(const float4*)(x + base);
    const float4 f1 = *(const float4*)(x + base + 4);
    short8 pk;
    pk[0] = __builtin_bit_cast(short, __float2bfloat16(f0.x));
    pk[1] = __builtin_bit_cast(short, __float2bfloat16(f0.y));
    pk[2] = __builtin_bit_cast(short, __float2bfloat16(f0.z));
    pk[3] = __builtin_bit_cast(short, __float2bfloat16(f0.w));
    pk[4] = __builtin_bit_cast(short, __float2bfloat16(f1.x));
    pk[5] = __builtin_bit_cast(short, __float2bfloat16(f1.y));
    pk[6] = __builtin_bit_cast(short, __float2bfloat16(f1.z));
    pk[7] = __builtin_bit_cast(short, __float2bfloat16(f1.w));
    *(short8*)((short*)y + base) = pk;
}

// ---------------- epilogue modes ----------------
enum { EPI_PLAIN = 0, EPI_NEG = 1, EPI_ADD1 = 2, EPI_P = 3, EPI_P_ROT = 4, EPI_PT = 5 };
// EPI_PT: C = acc + I + add1 + add2^T   (transposed add2 read, kills HoffT buffer)

// ---------------- async-staged GEMM core: C = A @ Bt^T ----------------
// 128x128 tile, BK=32, 256 threads, global_load_lds dwordx4 staging (m97 structure).
template <int EPI, bool OF32>
__device__ __forceinline__ void gemm_core(
    short* aT, short* bT,
    const bf16* __restrict__ A, const bf16* __restrict__ Bt, void* __restrict__ Cp,
    const int Nc, const int K, const int bx, const int by,
    const bf16* __restrict__ add1, const bf16* __restrict__ add2,
    const float* __restrict__ thetaP)
{
    const int tid = threadIdx.x;
    const int lane = tid & 63;
    const int quad = lane >> 4;
    const int l15 = lane & 15;
    const int wv = tid >> 6;
    const int wr = (wv >> 1) << 6;   // wave row offset: 0 or 64
    const int wc = (wv & 1) << 6;    // wave col offset: 0 or 64

    const short* Ag = (const short*)A + (size_t)(by << 7) * K;
    const short* Bg = (const short*)Bt + (size_t)(bx << 7) * K;

    floatx4 acc[4][4];
#pragma unroll
    for (int i = 0; i < 4; ++i)
#pragma unroll
        for (int j = 0; j < 4; ++j)
            acc[i][j] = (floatx4){0.f, 0.f, 0.f, 0.f};

    for (int k0 = 0; k0 < K; k0 += 32) {
        // 128x32 tiles = 512 x 16B chunks each; 2 chunks/thread, async DMA.
        // chunk ch -> LDS shorts [ch*8, ch*8+8) ; wave-uniform base + lane*16B.
#pragma unroll
        for (int c = 0; c < 2; ++c) {
            const int ch = (c << 8) + (wv << 6) + lane;
            const int row = ch >> 2;
            const int kp = (ch & 3) << 3;                 // short offset in row
            const int ldsBase = ((c << 8) + (wv << 6)) << 3;  // shorts, wave-uniform
            gl2lds16(Ag + (size_t)row * K + k0 + kp, aT + ldsBase);
            gl2lds16(Bg + (size_t)row * K + k0 + kp, bT + ldsBase);
        }
        __syncthreads();
        short8 af[4], bfr[4];
#pragma unroll
        for (int mi = 0; mi < 4; ++mi)
            af[mi] = *(const short8*)(aT + ((wr + (mi << 4) + l15) << 5) + (quad << 3));
#pragma unroll
        for (int ni = 0; ni < 4; ++ni)
            bfr[ni] = *(const short8*)(bT + ((wc + (ni << 4) + l15) << 5) + (quad << 3));
#pragma unroll
        for (int mi = 0; mi < 4; ++mi)
#pragma unroll
            for (int ni = 0; ni < 4; ++ni)
                acc[mi][ni] = __builtin_amdgcn_mfma_f32_16x16x32_bf16(af[mi], bfr[ni], acc[mi][ni], 0, 0, 0);
        __syncthreads();
    }

    float ct = 0.f, st = 0.f;
    if (EPI == EPI_P_ROT) {
        const float th = *thetaP;
        ct = cosf(th);
        st = sinf(th);
    }

    // C/D layout (m89-verified): col = lane&15, row = quad*4 + reg
#pragma unroll
    for (int mi = 0; mi < 4; ++mi) {
#pragma unroll
        for (int ni = 0; ni < 4; ++ni) {
#pragma unroll
            for (int r = 0; r < 4; ++r) {
                const int row = (by << 7) + wr + (mi << 4) + (quad << 2) + r;
                const int col = (bx << 7) + wc + (ni << 4) + l15;
                const size_t idx = (size_t)row * Nc + col;
                float v = acc[mi][ni][r];
                if (EPI == EPI_NEG) v = -v;
                if (EPI == EPI_ADD1) v += __bfloat162float(add1[idx]);
                if (EPI == EPI_P)
                    v += (row == col ? 1.f : 0.f)
                       + __bfloat162float(add1[idx]) + __bfloat162float(add2[idx]);
                if (EPI == EPI_PT)
                    v += (row == col ? 1.f : 0.f)
                       + __bfloat162float(add1[idx])
                       + __bfloat162float(add2[(size_t)col * Nc + row]);
                if (EPI == EPI_P_ROT) {
                    v += (row == col ? 1.f : 0.f)
                       + __bfloat162float(add1[idx]) + __bfloat162float(add2[idx]);
                    const float w = __shfl_xor(v, 1, 64);
                    v = (l15 & 1) ? (st * w + ct * v) : (ct * v - st * w);
                }
                if (OF32) ((float*)Cp)[idx] = v;
                else      ((bf16*)Cp)[idx] = __float2bfloat16(v);
            }
        }
    }
}

template <int EPI, bool OF32>
__launch_bounds__(256, 2) __global__
void gemm_one(const bf16* __restrict__ A, const bf16* __restrict__ Bt,
              void* __restrict__ Cp, const int Nc, const int K,
              const bf16* __restrict__ add1, const bf16* __restrict__ add2,
              const float* __restrict__ thetaP)
{
    __shared__ __attribute__((aligned(16))) short aT[128 * 32];
    __shared__ __attribute__((aligned(16))) short bT[128 * 32];
    const int nblk = Nc >> 7;
    const int b = xcd_swz(blockIdx.x, gridDim.x);
    gemm_core<EPI, OF32>(aT, bT, A, Bt, Cp, Nc, K, b % nblk, b / nblk,
                         add1, add2, thetaP);
}

// Two independent 2048^2 GEMMs in one dispatch (grid = 512 -> 2 blocks/CU).
template <int EPI0, int EPI1>
__launch_bounds__(256, 2) __global__
void gemm_dual(const bf16* A0, const bf16* B0, bf16* C0, const bf16* a10, const bf16* a20,
               const bf16* A1, const bf16* B1, bf16* C1, const bf16* a11, const bf16* a21,
               const float* thetaP)
{
    __shared__ __attribute__((aligned(16))) short aT[128 * 32];
    __shared__ __attribute__((aligned(16))) short bT[128 * 32];
    const int nblk = ND >> 7;          // 16
    const int nsub = nblk * nblk;      // 256
    int b = xcd_swz(blockIdx.x, gridDim.x);
    if (b < nsub) {
        gemm_core<EPI0, false>(aT, bT, A0, B0, (void*)C0, ND, ND, b % nblk, b / nblk, a10, a20, thetaP);
    } else {
        b -= nsub;
        gemm_core<EPI1, false>(aT, bT, A1, B1, (void*)C1, ND, ND, b % nblk, b / nblk, a11, a21, thetaP);
    }
}

// ================== 256x256 / BK=64 / 8-phase / counted-vmcnt big GEMM =======
// C(fp32)[M][Nc] = A(bf16)[M][K] @ Bt(bf16)[Nc][K]^T
// 512 threads = 8 waves (2M x 4N); per-wave 128x64 output; LDS 128 KiB static
// (2 dbuf x (256x64) x {A,B}).  T2 chunk-XOR swizzle applied identically on the
// pre-swizzled global source (linear global_load_lds dest) and the ds_read addr.
// R3: back to the R1 (m201-template) schedule — per-phase {ds_read burst; stage;
// barrier; lgkm(0); setprio; MFMA}, single counted vmcnt(6) per K-tile at P4 —
// now combined with the XCD swizzle (R2-proven: FETCH 270->100 MB) so staging
// DMA hits L2 (~200cy) instead of HBM (~900cy) and the vmcnt(6) depth covers it.
// Added m201's pre-barrier lgkmcnt(8) hint in the 12-read phase (P1).
// Staging stagger: tile T's halves issue at (T-2).p2 [A rows 0-63,128-191],
// (T-2).p3 [B rows 0-127], (T-2).p4 [B rows 128-255], (T-1).p1 [A rows 64-127,
// 192-255]; steady-state wait is vmcnt(6) once per K-tile, vmcnt(0) only for
// the last two tiles.

__device__ __forceinline__ void stage512(short* ldsT, const short* gT, const int K,
                                         const int kb, const int c0,
                                         const int wv, const int lane) {
    const int ch = c0 + (wv << 6) + lane;      // chunk index in 256x64 tile
    const int rw = ch >> 3;                    // row (8 chunks of 16B per row)
    const int cs = (ch & 7) ^ (rw & 7);        // inverse-swizzled source k-chunk
    gl2lds16(gT + (size_t)rw * K + kb + (cs << 3),
             ldsT + ((c0 + (wv << 6)) << 3));  // wave-uniform linear LDS dest
}

__device__ __forceinline__ void phase_mid() {
    __builtin_amdgcn_sched_barrier(0);
    __builtin_amdgcn_s_barrier();
    asm volatile("s_waitcnt lgkmcnt(0)" ::: "memory");
    __builtin_amdgcn_sched_barrier(0);
    __builtin_amdgcn_s_setprio(1);
}
__device__ __forceinline__ void phase_end() {
    __builtin_amdgcn_s_setprio(0);
    __builtin_amdgcn_sched_barrier(0);
    __builtin_amdgcn_s_barrier();
}

#define MFMA_BF16 __builtin_amdgcn_mfma_f32_16x16x32_bf16

__device__ __forceinline__ void tile256(
    short* Ac, short* Bc, short* An,
    const short* Ag, const short* Bg, const int K, const int nt, const int t,
    const int wv, const int lane, const int aBase, const int bBase,
    const int cOff0, const int cOff1, floatx4 (&acc)[8][4])
{
    short8 af[4][2], bb[4][2];
    const int kb1 = (t + 1) << 6;
    const int kb2 = (t + 2) << 6;

    // ---- phase 1: ds_read A rows mi0-3 + B ni0-1 (12 reads); stage (t+1)
    //      A-part2 -> An.  Pre-barrier lgkm(8) hint (m201: 12-read phase).
#pragma unroll
    for (int ml = 0; ml < 4; ++ml) {
        af[ml][0] = *(const short8*)(Ac + aBase + (ml << 10) + cOff0);
        af[ml][1] = *(const short8*)(Ac + aBase + (ml << 10) + cOff1);
    }
#pragma unroll
    for (int ni = 0; ni < 2; ++ni) {
        bb[ni][0] = *(const short8*)(Bc + bBase + (ni << 10) + cOff0);
        bb[ni][1] = *(const short8*)(Bc + bBase + (ni << 10) + cOff1);
    }
    if (t + 1 < nt) { stage512(An, Ag, K, kb1, 512, wv, lane); stage512(An, Ag, K, kb1, 1536, wv, lane); }
    __builtin_amdgcn_sched_barrier(0);
    asm volatile("s_waitcnt lgkmcnt(8)" ::: "memory");
    phase_mid();
#pragma unroll
    for (int ml = 0; ml < 4; ++ml)
#pragma unroll
        for (int ni = 0; ni < 2; ++ni) {
            acc[ml][ni] = MFMA_BF16(af[ml][0], bb[ni][0], acc[ml][ni], 0, 0, 0);
            acc[ml][ni] = MFMA_BF16(af[ml][1], bb[ni][1], acc[ml][ni], 0, 0, 0);
        }
    phase_end();

    // ---- phase 2: ds_read B ni2-3 ; stage (t+2) A-part1 -> Ac (rows read in p1)
#pragma unroll
    for (int ni = 2; ni < 4; ++ni) {
        bb[ni][0] = *(const short8*)(Bc + bBase + (ni << 10) + cOff0);
        bb[ni][1] = *(const short8*)(Bc + bBase + (ni << 10) + cOff1);
    }
    if (t + 2 < nt) { stage512(Ac, Ag, K, kb2, 0, wv, lane); stage512(Ac, Ag, K, kb2, 1024, wv, lane); }
    phase_mid();
#pragma unroll
    for (int ml = 0; ml < 4; ++ml)
#pragma unroll
        for (int ni = 2; ni < 4; ++ni) {
            acc[ml][ni] = MFMA_BF16(af[ml][0], bb[ni][0], acc[ml][ni], 0, 0, 0);
            acc[ml][ni] = MFMA_BF16(af[ml][1], bb[ni][1], acc[ml][ni], 0, 0, 0);
        }
    phase_end();

    // ---- phase 3: ds_read A rows mi4-7 ; stage (t+2) B rows 0-127 (read p1/p2)
#pragma unroll
    for (int ml = 0; ml < 4; ++ml) {
        af[ml][0] = *(const short8*)(Ac + aBase + 4096 + (ml << 10) + cOff0);
        af[ml][1] = *(const short8*)(Ac + aBase + 4096 + (ml << 10) + cOff1);
    }
    if (t + 2 < nt) { stage512(Bc, Bg, K, kb2, 0, wv, lane); stage512(Bc, Bg, K, kb2, 512, wv, lane); }
    phase_mid();
#pragma unroll
    for (int ml = 0; ml < 4; ++ml)
#pragma unroll
        for (int ni = 0; ni < 2; ++ni) {
            acc[4 + ml][ni] = MFMA_BF16(af[ml][0], bb[ni][0], acc[4 + ml][ni], 0, 0, 0);
            acc[4 + ml][ni] = MFMA_BF16(af[ml][1], bb[ni][1], acc[4 + ml][ni], 0, 0, 0);
        }
    phase_end();

    // ---- phase 4: stage (t+2) B rows 128-255 ; counted vmcnt for tile t+1
    if (t + 2 < nt) { stage512(Bc, Bg, K, kb2, 1024, wv, lane); stage512(Bc, Bg, K, kb2, 1536, wv, lane); }
    __builtin_amdgcn_sched_barrier(0);
    if (t < nt - 2) asm volatile("s_waitcnt vmcnt(6)" ::: "memory");
    else            asm volatile("s_waitcnt vmcnt(0)" ::: "memory");
    __builtin_amdgcn_s_barrier();
    __builtin_amdgcn_sched_barrier(0);
    __builtin_amdgcn_s_setprio(1);
#pragma unroll
    for (int ml = 0; ml < 4; ++ml)
#pragma unroll
        for (int ni = 2; ni < 4; ++ni) {
            acc[4 + ml][ni] = MFMA_BF16(af[ml][0], bb[ni][0], acc[4 + ml][ni], 0, 0, 0);
            acc[4 + ml][ni] = MFMA_BF16(af[ml][1], bb[ni][1], acc[4 + ml][ni], 0, 0, 0);
        }
    phase_end();
}

__launch_bounds__(512, 2) __global__
void gemm_big256(const bf16* __restrict__ A, const bf16* __restrict__ Bt,
                 float* __restrict__ C, const int Nc, const int K)
{
    __shared__ __attribute__((aligned(16))) short smem[65536];   // 128 KiB
    short* A0s = smem;
    short* A1s = smem + 16384;
    short* B0s = smem + 32768;
    short* B1s = smem + 49152;

    const int nblkx = Nc >> 8;                 // 8
    const int b = xcd_swz(blockIdx.x, gridDim.x);
    const int bx = b % nblkx;
    const int by = b / nblkx;
    const int tid = threadIdx.x;
    const int lane = tid & 63;
    const int q = lane >> 4;
    const int l15 = lane & 15;
    const int wv = tid >> 6;                   // 0..7
    const int wm = wv >> 2;                    // 0..1 (row half)
    const int wn = wv & 3;                     // 0..3 (col quarter)

    const short* Ag = (const short*)A + (size_t)(by << 8) * K;
    const short* Bg = (const short*)Bt + (size_t)(bx << 8) * K;

    // ds_read offsets (shorts). row&7 == l15&7 for all fragment rows, so the
    // swizzled k-chunk is ((q + 4*kk) ^ (l15&7)).
    const int swz = l15 & 7;
    const int aBase = ((wm << 7) + l15) << 6;  // (wm*128 + l15) * 64
    const int bBase = ((wn << 6) + l15) << 6;  // (wn*64  + l15) * 64
    const int cOff0 = (q ^ swz) << 3;
    const int cOff1 = ((q + 4) ^ swz) << 3;

    floatx4 acc[8][4];
#pragma unroll
    for (int i = 0; i < 8; ++i)
#pragma unroll
        for (int j = 0; j < 4; ++j)
            acc[i][j] = (floatx4){0.f, 0.f, 0.f, 0.f};

    const int nt = K >> 6;                     // 32 K-tiles of 64

    // prologue: T0 full (8 loads) + T1 {A-part1, B-full} (6 loads); wait T0.
    stage512(A0s, Ag, K, 0, 0,    wv, lane);
    stage512(A0s, Ag, K, 0, 512,  wv, lane);
    stage512(A0s, Ag, K, 0, 1024, wv, lane);
    stage512(A0s, Ag, K, 0, 1536, wv, lane);
    stage512(B0s, Bg, K, 0, 0,    wv, lane);
    stage512(B0s, Bg, K, 0, 512,  wv, lane);
    stage512(B0s, Bg, K, 0, 1024, wv, lane);
    stage512(B0s, Bg, K, 0, 1536, wv, lane);
    stage512(A1s, Ag, K, 64, 0,    wv, lane);
    stage512(A1s, Ag, K, 64, 1024, wv, lane);
    stage512(B1s, Bg, K, 64, 0,    wv, lane);
    stage512(B1s, Bg, K, 64, 512,  wv, lane);
    stage512(B1s, Bg, K, 64, 1024, wv, lane);
    stage512(B1s, Bg, K, 64, 1536, wv, lane);
    __builtin_amdgcn_sched_barrier(0);
    asm volatile("s_waitcnt vmcnt(6)" ::: "memory");   // T0 resident
    __builtin_amdgcn_s_barrier();

    for (int t = 0; t < nt; t += 2) {
        tile256(A0s, B0s, A1s, Ag, Bg, K, nt, t,     wv, lane, aBase, bBase, cOff0, cOff1, acc);
        tile256(A1s, B1s, A0s, Ag, Bg, K, nt, t + 1, wv, lane, aBase, bBase, cOff0, cOff1, acc);
    }

    // epilogue: C/D layout col = lane&15, row = quad*4 + reg (m89-verified)
#pragma unroll
    for (int mi = 0; mi < 8; ++mi)
#pragma unroll
        for (int ni = 0; ni < 4; ++ni)
#pragma unroll
            for (int r = 0; r < 4; ++r) {
                const int row = (by << 8) + (wm << 7) + (mi << 4) + (q << 2) + r;
                const int col = (bx << 8) + (wn << 6) + (ni << 4) + l15;
                C[(size_t)row * Nc + col] = acc[mi][ni][r];
            }
}

// ---------------- Tier-B (round-2 proven) manual-staging GEMM ----------------
template <int EPI, bool AF32, bool OF32>
__launch_bounds__(256, 2) __global__
void gemm_bt(const void* __restrict__ Ap, const bf16* __restrict__ Bt,
             void* __restrict__ Cp, const int Nc, const int K,
             const bf16* __restrict__ add1, const bf16* __restrict__ add2,
             const float* __restrict__ thetaP)
{
    __shared__ __attribute__((aligned(16))) short aT[128 * 32];
    __shared__ __attribute__((aligned(16))) short bT[128 * 32];

    const int nblk = Nc >> 7;
    const int bx = blockIdx.x % nblk;
    const int by = blockIdx.x / nblk;
    const int tid = threadIdx.x;
    const int lane = tid & 63;
    const int quad = lane >> 4;
    const int l15 = lane & 15;
    const int wv = tid >> 6;
    const int wr = (wv >> 1) << 6;
    const int wc = (wv & 1) << 6;

    const short* Ag = (const short*)Ap + (size_t)(by << 7) * K;
    const float* Agf = (const float*)Ap + (size_t)(by << 7) * K;
    const short* Bg = (const short*)Bt + (size_t)(bx << 7) * K;

    floatx4 acc[4][4];
#pragma unroll
    for (int i = 0; i < 4; ++i)
#pragma unroll
        for (int j = 0; j < 4; ++j)
            acc[i][j] = (floatx4){0.f, 0.f, 0.f, 0.f};

    for (int k0 = 0; k0 < K; k0 += 32) {
#pragma unroll
        for (int c = 0; c < 2; ++c) {
            const int ch = tid + (c << 8);
            const int row = ch >> 2;
            const int kp = (ch & 3) << 3;
            if (AF32) {
                const float4 f0 = *(const float4*)(Agf + (size_t)row * K + k0 + kp);
                const float4 f1 = *(const float4*)(Agf + (size_t)row * K + k0 + kp + 4);
                short8 pk;
                pk[0] = __builtin_bit_cast(short, __float2bfloat16(f0.x));
                pk[1] = __builtin_bit_cast(short, __float2bfloat16(f0.y));
                pk[2] = __builtin_bit_cast(short, __float2bfloat16(f0.z));
                pk[3] = __builtin_bit_cast(short, __float2bfloat16(f0.w));
                pk[4] = __builtin_bit_cast(short, __float2bfloat16(f1.x));
                pk[5] = __builtin_bit_cast(short, __float2bfloat16(f1.y));
                pk[6] = __builtin_bit_cast(short, __float2bfloat16(f1.z));
                pk[7] = __builtin_bit_cast(short, __float2bfloat16(f1.w));
                *(short8*)(aT + (row << 5) + kp) = pk;
            } else {
                *(int4*)(aT + (row << 5) + kp) = *(const int4*)(Ag + (size_t)row * K + k0 + kp);
            }
            *(int4*)(bT + (row << 5) + kp) = *(const int4*)(Bg + (size_t)row * K + k0 + kp);
        }
        __syncthreads();
        short8 af[4], bfr[4];
#pragma unroll
        for (int mi = 0; mi < 4; ++mi)
            af[mi] = *(const short8*)(aT + ((wr + (mi << 4) + l15) << 5) + (quad << 3));
#pragma unroll
        for (int ni = 0; ni < 4; ++ni)
            bfr[ni] = *(const short8*)(bT + ((wc + (ni << 4) + l15) << 5) + (quad << 3));
#pragma unroll
        for (int mi = 0; mi < 4; ++mi)
#pragma unroll
            for (int ni = 0; ni < 4; ++ni)
                acc[mi][ni] = __builtin_amdgcn_mfma_f32_16x16x32_bf16(af[mi], bfr[ni], acc[mi][ni], 0, 0, 0);
        __syncthreads();
    }

    float ct = 0.f, st = 0.f;
    if (EPI == EPI_P_ROT) {
        const float th = *thetaP;
        ct = cosf(th);
        st = sinf(th);
    }

#pragma unroll
    for (int mi = 0; mi < 4; ++mi) {
#pragma unroll
        for (int ni = 0; ni < 4; ++ni) {
#pragma unroll
            for (int r = 0; r < 4; ++r) {
                const int row = (by << 7) + wr + (mi << 4) + (quad << 2) + r;
                const int col = (bx << 7) + wc + (ni << 4) + l15;
                const size_t idx = (size_t)row * Nc + col;
                float v = acc[mi][ni][r];
                if (EPI == EPI_NEG) v = -v;
                if (EPI == EPI_ADD1) v += __bfloat162float(add1[idx]);
                if (EPI == EPI_P || EPI == EPI_P_ROT)
                    v += (row == col ? 1.f : 0.f)
                       + __bfloat162float(add1[idx]) + __bfloat162float(add2[idx]);
                if (EPI == EPI_P_ROT) {
                    const float w = __shfl_xor(v, 1, 64);
                    v = (l15 & 1) ? (st * w + ct * v) : (ct * v - st * w);
                }
                if (OF32) ((float*)Cp)[idx] = v;
                else      ((bf16*)Cp)[idx] = __float2bfloat16(v);
            }
        }
    }
}

// ---------------- launch ----------------
// out = x @ P1 @ R @ P2,  P = (I+M)^2 (I+M^2+M^4),  M = 0.5(W^T - W)
// Tier A (ws >= 6*ND^2*2 + tokens*ND*2 bytes): dual-batched chains + async GEMM + bf16 x;
//   final big GEMM: 256^2/BK=64/8-phase (R1 schedule) + XCD swizzle.
// Tier B: round-2 proven sequence (5 buffers, fp32 A staging on the big GEMM).

extern "C" void kernel_launch(void* const* d_in, const int* in_sizes, int n_in,
                              void* d_out, int out_size, void* d_ws, size_t ws_size,
                              hipStream_t stream)
{
    const float* x = (const float*)d_in[0];
    const float* u1 = (const float*)d_in[1];
    const float* u2 = (const float*)d_in[2];
    const float* th = (const float*)d_in[3];
    float* out = (float*)d_out;
    const int tokens = in_sizes[0] / ND;

    const size_t MAT = (size_t)ND * ND;
    const size_t XBE = (size_t)tokens * ND;

    const dim3 blk(256);
    const int gSkew = (ND / 32) * (ND / 32);
    const int gElem = (int)(MAT / 256);
    const int gSm = (ND / 128) * (ND / 128);        // 256
    const int gBig = (tokens / 128) * (ND / 128);   // 2048

    if (ws_size >= (6 * MAT + XBE) * sizeof(bf16)) {
        // ---------------- Tier A ----------------
        bf16* base = (bf16*)d_ws;
        bf16* b0 = base;            // M2 -> P2T
        bf16* b1 = base + MAT;      // M1 -> P1R
        bf16* b2 = base + 2 * MAT;  // Msq2 -> Hoff2 -> QT
        bf16* b3 = base + 3 * MAT;  // Msq1 -> Hoff1
        bf16* b4 = base + 4 * MAT;  // Goff2
        bf16* b5 = base + 5 * MAT;  // Goff1
        bf16* xb = base + 6 * MAT;  // x as bf16

        convert_f32_bf16<<<(int)(XBE / 2048), blk, 0, stream>>>(x, xb);
        build_skew<<<gSkew, blk, 0, stream>>>(u2, b0);   // M2
        build_skew<<<gSkew, blk, 0, stream>>>(u1, b1);   // M1
        // Msq = -(M @ M^T)  (M skew)
        gemm_dual<EPI_NEG, EPI_NEG><<<2 * gSm, blk, 0, stream>>>(
            b0, b0, b2, nullptr, nullptr,  b1, b1, b3, nullptr, nullptr, nullptr);
        // Goff = Msq@Msq + Msq   (Msq symmetric)
        gemm_dual<EPI_ADD1, EPI_ADD1><<<2 * gSm, blk, 0, stream>>>(
            b2, b2, b4, b2, nullptr,  b3, b3, b5, b3, nullptr, nullptr);
        // Hoff = 2M + Msq (in place over Msq)
        build_hoff1<<<gElem, blk, 0, stream>>>(b0, b2, b2);   // Hoff2
        build_hoff1<<<gElem, blk, 0, stream>>>(b1, b3, b3);   // Hoff1
        // P2T = I + Goff2 + Hoff2^T + Goff2@Hoff2^T  (PT: transposed add2)
        // P1R = (I + Goff1 + Hoff1 + Hoff1@Goff1) @ R
        gemm_dual<EPI_PT, EPI_P_ROT><<<2 * gSm, blk, 0, stream>>>(
            b4, b2, b0, b4, b2,  b3, b5, b1, b5, b3, th);
        // QT = P2T @ (P1R)^T
        gemm_one<EPI_PLAIN, false><<<gSm, blk, 0, stream>>>(b0, b1, b2, ND, ND, nullptr, nullptr, nullptr);
        // out = x @ QT^T  -- 256x256 8-phase kernel (fallback: old 128x128 path)
        if ((tokens & 255) == 0) {
            const int gBig256 = (tokens >> 8) * (ND >> 8);   // 512
            gemm_big256<<<gBig256, dim3(512), 0, stream>>>(xb, b2, out, ND, ND);
        } else {
            gemm_one<EPI_PLAIN, true><<<gBig, blk, 0, stream>>>(xb, b2, out, ND, ND, nullptr, nullptr, nullptr);
        }
    } else {
        // ---------------- Tier B (round-2 proven) ----------------
        bf16* A = (bf16*)d_ws;
        bf16* B = A + MAT;
        bf16* Cb = B + MAT;
        bf16* D = Cb + MAT;
        bf16* E = D + MAT;

        build_skew<<<gSkew, blk, 0, stream>>>(u2, A);
        gemm_bt<EPI_NEG, false, false><<<gSm, blk, 0, stream>>>(A, A, B, ND, ND, nullptr, nullptr, nullptr);
        gemm_bt<EPI_ADD1, false, false><<<gSm, blk, 0, stream>>>(B, B, Cb, ND, ND, B, nullptr, nullptr);
        build_hoff<<<gElem, blk, 0, stream>>>(A, B, D, E);
        gemm_bt<EPI_P, false, false><<<gSm, blk, 0, stream>>>(Cb, D, A, ND, ND, Cb, E, nullptr);

        build_skew<<<gSkew, blk, 0, stream>>>(u1, B);
        gemm_bt<EPI_NEG, false, false><<<gSm, blk, 0, stream>>>(B, B, Cb, ND, ND, nullptr, nullptr, nullptr);
        gemm_bt<EPI_ADD1, false, false><<<gSm, blk, 0, stream>>>(Cb, Cb, D, ND, ND, Cb, nullptr, nullptr);
        build_hoff<<<gElem, blk, 0, stream>>>(B, Cb, E, B);
        gemm_bt<EPI_P_ROT, false, false><<<gSm, blk, 0, stream>>>(E, D, Cb, ND, ND, D, E, th);

        gemm_bt<EPI_PLAIN, false, false><<<gSm, blk, 0, stream>>>(A, Cb, D, ND, ND, nullptr, nullptr, nullptr);
        gemm_bt<EPI_PLAIN, true, true><<<gBig, blk, 0, stream>>>(x, D, out, ND, ND, nullptr, nullptr, nullptr);
    }
}

// Round 4
// 563.923 us; speedup vs baseline: 1.1075x; 1.0137x over previous
//
#include <hip/hip_runtime.h>
#include <hip/hip_bf16.h>

#define ND 2048

using bf16 = __hip_bfloat16;
using short8 = __attribute__((ext_vector_type(8))) short;   // 8 bf16 = 4 VGPRs
using floatx4 = __attribute__((ext_vector_type(4))) float;

// ---------------- async global->LDS (16B per lane, wave-uniform LDS base) ----
__device__ __forceinline__ void gl2lds16(const short* g, short* l) {
    __builtin_amdgcn_global_load_lds(
        (const __attribute__((address_space(1))) unsigned int*)g,
        (__attribute__((address_space(3))) unsigned int*)l,
        16, 0, 0);
}

// chunked bijective XCD swizzle (requires grid % 8 == 0)
__device__ __forceinline__ int xcd_swz(int b, int g) {
    if ((g & 7) == 0) b = (b & 7) * (g >> 3) + (b >> 3);
    return b;
}

// ---------------- elementwise kernels ----------------

// Two skew builds in one dispatch: M = 0.5*(u^T - u), fp32 in -> bf16 out.
__global__ void build_skew2(const float* __restrict__ uA, bf16* __restrict__ MA,
                            const float* __restrict__ uB, bf16* __restrict__ MB) {
    __shared__ float t[32][33];
    const int nb = (ND / 32) * (ND / 32);
    int b = blockIdx.x;
    const float* u = uA;
    bf16* M = MA;
    if (b >= nb) { b -= nb; u = uB; M = MB; }
    const int bx = b & (ND / 32 - 1);
    const int by = b / (ND / 32);
    const int tx = threadIdx.x & 31;
    const int ty = threadIdx.x >> 5;   // 0..7
#pragma unroll
    for (int rr = 0; rr < 4; ++rr) {
        const int r = ty * 4 + rr;
        t[tx][r] = u[(size_t)(bx * 32 + r) * ND + by * 32 + tx];
    }
    __syncthreads();
#pragma unroll
    for (int rr = 0; rr < 4; ++rr) {
        const int r = ty * 4 + rr;
        const size_t idx = (size_t)(by * 32 + r) * ND + bx * 32 + tx;
        M[idx] = __float2bfloat16(0.5f * (t[r][tx] - u[idx]));
    }
}

// Merged, x8-vectorized hoff builder.
// First half of grid (chain2): H2 = 2*M2 + Q2 (in place over Q2),
//                              HT2 = Q2 - 2*M2 (in place over M2) = Hoff2^T bit-exact.
// Second half (chain1):        H1 = 2*M1 + Q1 (in place over Q1).
// Aliased in/out pointers are same-index read-then-write per thread -> safe.
__global__ void build_hoffs(const bf16* M2, const bf16* Q2, bf16* H2, bf16* HT2,
                            const bf16* M1, const bf16* Q1, bf16* H1) {
    const size_t nper = (size_t)ND * ND / 8;     // short8 groups per matrix
    size_t g = (size_t)blockIdx.x * 256 + threadIdx.x;
    const bool second = (g >= nper);
    if (second) g -= nper;
    const size_t i8 = g * 8;
    const short8 mv = *(const short8*)((const short*)(second ? M1 : M2) + i8);
    const short8 qv = *(const short8*)((const short*)(second ? Q1 : Q2) + i8);
    short8 h, ht;
#pragma unroll
    for (int j = 0; j < 8; ++j) {
        const float m = __bfloat162float(__builtin_bit_cast(bf16, (short)mv[j]));
        const float q = __bfloat162float(__builtin_bit_cast(bf16, (short)qv[j]));
        h[j]  = __builtin_bit_cast(short, __float2bfloat16(2.f * m + q));
        ht[j] = __builtin_bit_cast(short, __float2bfloat16(q - 2.f * m));
    }
    if (second) {
        *(short8*)((short*)H1 + i8) = h;
    } else {
        *(short8*)((short*)H2 + i8) = h;
        *(short8*)((short*)HT2 + i8) = ht;
    }
}

// Tier-B variant: Hoff = 2M + Msq, HoffT = -2M + Msq (aliasing allowed)
__global__ void build_hoff(const bf16* M, const bf16* Msq, bf16* Hoff, bf16* HoffT) {
    const size_t idx = (size_t)blockIdx.x * 256 + threadIdx.x;
    const float m = __bfloat162float(M[idx]);
    const float q = __bfloat162float(Msq[idx]);
    Hoff[idx] = __float2bfloat16(2.f * m + q);
    HoffT[idx] = __float2bfloat16(q - 2.f * m);
}

// x fp32 -> bf16, 8 elems/thread
__global__ void convert_f32_bf16(const float* __restrict__ x, bf16* __restrict__ y) {
    const size_t base = ((size_t)blockIdx.x * 256 + threadIdx.x) * 8;
    const float4 f0 = *(const float4*)(x + base);
    const float4 f1 = *(const float4*)(x + base + 4);
    short8 pk;
    pk[0] = __builtin_bit_cast(short, __float2bfloat16(f0.x));
    pk[1] = __builtin_bit_cast(short, __float2bfloat16(f0.y));
    pk[2] = __builtin_bit_cast(short, __float2bfloat16(f0.z));
    pk[3] = __builtin_bit_cast(short, __float2bfloat16(f0.w));
    pk[4] = __builtin_bit_cast(short, __float2bfloat16(f1.x));
    pk[5] = __builtin_bit_cast(short, __float2bfloat16(f1.y));
    pk[6] = __builtin_bit_cast(short, __float2bfloat16(f1.z));
    pk[7] = __builtin_bit_cast(short, __float2bfloat16(f1.w));
    *(short8*)((short*)y + base) = pk;
}

// ---------------- epilogue modes ----------------
enum { EPI_PLAIN = 0, EPI_NEG = 1, EPI_ADD1 = 2, EPI_P = 3, EPI_P_ROT = 4 };

// ---------------- async-staged GEMM core: C = A @ Bt^T ----------------
// 128x128 tile, BK=32, 256 threads, global_load_lds dwordx4 staging (m97 structure).
template <int EPI, bool OF32>
__device__ __forceinline__ void gemm_core(
    short* aT, short* bT,
    const bf16* __restrict__ A, const bf16* __restrict__ Bt, void* __restrict__ Cp,
    const int Nc, const int K, const int bx, const int by,
    const bf16* __restrict__ add1, const bf16* __restrict__ add2,
    const float* __restrict__ thetaP)
{
    const int tid = threadIdx.x;
    const int lane = tid & 63;
    const int quad = lane >> 4;
    const int l15 = lane & 15;
    const int wv = tid >> 6;
    const int wr = (wv >> 1) << 6;   // wave row offset: 0 or 64
    const int wc = (wv & 1) << 6;    // wave col offset: 0 or 64

    const short* Ag = (const short*)A + (size_t)(by << 7) * K;
    const short* Bg = (const short*)Bt + (size_t)(bx << 7) * K;

    floatx4 acc[4][4];
#pragma unroll
    for (int i = 0; i < 4; ++i)
#pragma unroll
        for (int j = 0; j < 4; ++j)
            acc[i][j] = (floatx4){0.f, 0.f, 0.f, 0.f};

    for (int k0 = 0; k0 < K; k0 += 32) {
#pragma unroll
        for (int c = 0; c < 2; ++c) {
            const int ch = (c << 8) + (wv << 6) + lane;
            const int row = ch >> 2;
            const int kp = (ch & 3) << 3;                 // short offset in row
            const int ldsBase = ((c << 8) + (wv << 6)) << 3;  // shorts, wave-uniform
            gl2lds16(Ag + (size_t)row * K + k0 + kp, aT + ldsBase);
            gl2lds16(Bg + (size_t)row * K + k0 + kp, bT + ldsBase);
        }
        __syncthreads();
        short8 af[4], bfr[4];
#pragma unroll
        for (int mi = 0; mi < 4; ++mi)
            af[mi] = *(const short8*)(aT + ((wr + (mi << 4) + l15) << 5) + (quad << 3));
#pragma unroll
        for (int ni = 0; ni < 4; ++ni)
            bfr[ni] = *(const short8*)(bT + ((wc + (ni << 4) + l15) << 5) + (quad << 3));
#pragma unroll
        for (int mi = 0; mi < 4; ++mi)
#pragma unroll
            for (int ni = 0; ni < 4; ++ni)
                acc[mi][ni] = __builtin_amdgcn_mfma_f32_16x16x32_bf16(af[mi], bfr[ni], acc[mi][ni], 0, 0, 0);
        __syncthreads();
    }

    float ct = 0.f, st = 0.f;
    if (EPI == EPI_P_ROT) {
        const float th = *thetaP;
        ct = cosf(th);
        st = sinf(th);
    }

    // C/D layout (m89-verified): col = lane&15, row = quad*4 + reg
#pragma unroll
    for (int mi = 0; mi < 4; ++mi) {
#pragma unroll
        for (int ni = 0; ni < 4; ++ni) {
#pragma unroll
            for (int r = 0; r < 4; ++r) {
                const int row = (by << 7) + wr + (mi << 4) + (quad << 2) + r;
                const int col = (bx << 7) + wc + (ni << 4) + l15;
                const size_t idx = (size_t)row * Nc + col;
                float v = acc[mi][ni][r];
                if (EPI == EPI_NEG) v = -v;
                if (EPI == EPI_ADD1) v += __bfloat162float(add1[idx]);
                if (EPI == EPI_P)
                    v += (row == col ? 1.f : 0.f)
                       + __bfloat162float(add1[idx]) + __bfloat162float(add2[idx]);
                if (EPI == EPI_P_ROT) {
                    v += (row == col ? 1.f : 0.f)
                       + __bfloat162float(add1[idx]) + __bfloat162float(add2[idx]);
                    const float w = __shfl_xor(v, 1, 64);
                    v = (l15 & 1) ? (st * w + ct * v) : (ct * v - st * w);
                }
                if (OF32) ((float*)Cp)[idx] = v;
                else      ((bf16*)Cp)[idx] = __float2bfloat16(v);
            }
        }
    }
}

template <int EPI, bool OF32>
__launch_bounds__(256, 2) __global__
void gemm_one(const bf16* __restrict__ A, const bf16* __restrict__ Bt,
              void* __restrict__ Cp, const int Nc, const int K,
              const bf16* __restrict__ add1, const bf16* __restrict__ add2,
              const float* __restrict__ thetaP)
{
    __shared__ __attribute__((aligned(16))) short aT[128 * 32];
    __shared__ __attribute__((aligned(16))) short bT[128 * 32];
    const int nblk = Nc >> 7;
    const int b = xcd_swz(blockIdx.x, gridDim.x);
    gemm_core<EPI, OF32>(aT, bT, A, Bt, Cp, Nc, K, b % nblk, b / nblk,
                         add1, add2, thetaP);
}

// Two independent 2048^2 GEMMs in one dispatch (grid = 512 -> 2 blocks/CU).
template <int EPI0, int EPI1>
__launch_bounds__(256, 2) __global__
void gemm_dual(const bf16* A0, const bf16* B0, bf16* C0, const bf16* a10, const bf16* a20,
               const bf16* A1, const bf16* B1, bf16* C1, const bf16* a11, const bf16* a21,
               const float* thetaP)
{
    __shared__ __attribute__((aligned(16))) short aT[128 * 32];
    __shared__ __attribute__((aligned(16))) short bT[128 * 32];
    const int nblk = ND >> 7;          // 16
    const int nsub = nblk * nblk;      // 256
    int b = xcd_swz(blockIdx.x, gridDim.x);
    if (b < nsub) {
        gemm_core<EPI0, false>(aT, bT, A0, B0, (void*)C0, ND, ND, b % nblk, b / nblk, a10, a20, thetaP);
    } else {
        b -= nsub;
        gemm_core<EPI1, false>(aT, bT, A1, B1, (void*)C1, ND, ND, b % nblk, b / nblk, a11, a21, thetaP);
    }
}

// ================== 256x256 / BK=64 / 8-phase / counted-vmcnt big GEMM =======
// (R3-proven: 141 us, MfmaUtil 41%, 0 bank conflicts, FETCH 98 MB.  Frozen.)

__device__ __forceinline__ void stage512(short* ldsT, const short* gT, const int K,
                                         const int kb, const int c0,
                                         const int wv, const int lane) {
    const int ch = c0 + (wv << 6) + lane;      // chunk index in 256x64 tile
    const int rw = ch >> 3;                    // row (8 chunks of 16B per row)
    const int cs = (ch & 7) ^ (rw & 7);        // inverse-swizzled source k-chunk
    gl2lds16(gT + (size_t)rw * K + kb + (cs << 3),
             ldsT + ((c0 + (wv << 6)) << 3));  // wave-uniform linear LDS dest
}

__device__ __forceinline__ void phase_mid() {
    __builtin_amdgcn_sched_barrier(0);
    __builtin_amdgcn_s_barrier();
    asm volatile("s_waitcnt lgkmcnt(0)" ::: "memory");
    __builtin_amdgcn_sched_barrier(0);
    __builtin_amdgcn_s_setprio(1);
}
__device__ __forceinline__ void phase_end() {
    __builtin_amdgcn_s_setprio(0);
    __builtin_amdgcn_sched_barrier(0);
    __builtin_amdgcn_s_barrier();
}

#define MFMA_BF16 __builtin_amdgcn_mfma_f32_16x16x32_bf16

__device__ __forceinline__ void tile256(
    short* Ac, short* Bc, short* An,
    const short* Ag, const short* Bg, const int K, const int nt, const int t,
    const int wv, const int lane, const int aBase, const int bBase,
    const int cOff0, const int cOff1, floatx4 (&acc)[8][4])
{
    short8 af[4][2], bb[4][2];
    const int kb1 = (t + 1) << 6;
    const int kb2 = (t + 2) << 6;

    // ---- phase 1: ds_read A rows mi0-3 + B ni0-1 (12 reads); stage (t+1) A2 -> An
#pragma unroll
    for (int ml = 0; ml < 4; ++ml) {
        af[ml][0] = *(const short8*)(Ac + aBase + (ml << 10) + cOff0);
        af[ml][1] = *(const short8*)(Ac + aBase + (ml << 10) + cOff1);
    }
#pragma unroll
    for (int ni = 0; ni < 2; ++ni) {
        bb[ni][0] = *(const short8*)(Bc + bBase + (ni << 10) + cOff0);
        bb[ni][1] = *(const short8*)(Bc + bBase + (ni << 10) + cOff1);
    }
    if (t + 1 < nt) { stage512(An, Ag, K, kb1, 512, wv, lane); stage512(An, Ag, K, kb1, 1536, wv, lane); }
    __builtin_amdgcn_sched_barrier(0);
    asm volatile("s_waitcnt lgkmcnt(8)" ::: "memory");
    phase_mid();
#pragma unroll
    for (int ml = 0; ml < 4; ++ml)
#pragma unroll
        for (int ni = 0; ni < 2; ++ni) {
            acc[ml][ni] = MFMA_BF16(af[ml][0], bb[ni][0], acc[ml][ni], 0, 0, 0);
            acc[ml][ni] = MFMA_BF16(af[ml][1], bb[ni][1], acc[ml][ni], 0, 0, 0);
        }
    phase_end();

    // ---- phase 2: ds_read B ni2-3 ; stage (t+2) A1 -> Ac
#pragma unroll
    for (int ni = 2; ni < 4; ++ni) {
        bb[ni][0] = *(const short8*)(Bc + bBase + (ni << 10) + cOff0);
        bb[ni][1] = *(const short8*)(Bc + bBase + (ni << 10) + cOff1);
    }
    if (t + 2 < nt) { stage512(Ac, Ag, K, kb2, 0, wv, lane); stage512(Ac, Ag, K, kb2, 1024, wv, lane); }
    phase_mid();
#pragma unroll
    for (int ml = 0; ml < 4; ++ml)
#pragma unroll
        for (int ni = 2; ni < 4; ++ni) {
            acc[ml][ni] = MFMA_BF16(af[ml][0], bb[ni][0], acc[ml][ni], 0, 0, 0);
            acc[ml][ni] = MFMA_BF16(af[ml][1], bb[ni][1], acc[ml][ni], 0, 0, 0);
        }
    phase_end();

    // ---- phase 3: ds_read A rows mi4-7 ; stage (t+2) B rows 0-127
#pragma unroll
    for (int ml = 0; ml < 4; ++ml) {
        af[ml][0] = *(const short8*)(Ac + aBase + 4096 + (ml << 10) + cOff0);
        af[ml][1] = *(const short8*)(Ac + aBase + 4096 + (ml << 10) + cOff1);
    }
    if (t + 2 < nt) { stage512(Bc, Bg, K, kb2, 0, wv, lane); stage512(Bc, Bg, K, kb2, 512, wv, lane); }
    phase_mid();
#pragma unroll
    for (int ml = 0; ml < 4; ++ml)
#pragma unroll
        for (int ni = 0; ni < 2; ++ni) {
            acc[4 + ml][ni] = MFMA_BF16(af[ml][0], bb[ni][0], acc[4 + ml][ni], 0, 0, 0);
            acc[4 + ml][ni] = MFMA_BF16(af[ml][1], bb[ni][1], acc[4 + ml][ni], 0, 0, 0);
        }
    phase_end();

    // ---- phase 4: stage (t+2) B rows 128-255 ; counted vmcnt for tile t+1
    if (t + 2 < nt) { stage512(Bc, Bg, K, kb2, 1024, wv, lane); stage512(Bc, Bg, K, kb2, 1536, wv, lane); }
    __builtin_amdgcn_sched_barrier(0);
    if (t < nt - 2) asm volatile("s_waitcnt vmcnt(6)" ::: "memory");
    else            asm volatile("s_waitcnt vmcnt(0)" ::: "memory");
    __builtin_amdgcn_s_barrier();
    __builtin_amdgcn_sched_barrier(0);
    __builtin_amdgcn_s_setprio(1);
#pragma unroll
    for (int ml = 0; ml < 4; ++ml)
#pragma unroll
        for (int ni = 2; ni < 4; ++ni) {
            acc[4 + ml][ni] = MFMA_BF16(af[ml][0], bb[ni][0], acc[4 + ml][ni], 0, 0, 0);
            acc[4 + ml][ni] = MFMA_BF16(af[ml][1], bb[ni][1], acc[4 + ml][ni], 0, 0, 0);
        }
    phase_end();
}

__launch_bounds__(512, 2) __global__
void gemm_big256(const bf16* __restrict__ A, const bf16* __restrict__ Bt,
                 float* __restrict__ C, const int Nc, const int K)
{
    __shared__ __attribute__((aligned(16))) short smem[65536];   // 128 KiB
    short* A0s = smem;
    short* A1s = smem + 16384;
    short* B0s = smem + 32768;
    short* B1s = smem + 49152;

    const int nblkx = Nc >> 8;                 // 8
    const int b = xcd_swz(blockIdx.x, gridDim.x);
    const int bx = b % nblkx;
    const int by = b / nblkx;
    const int tid = threadIdx.x;
    const int lane = tid & 63;
    const int q = lane >> 4;
    const int l15 = lane & 15;
    const int wv = tid >> 6;                   // 0..7
    const int wm = wv >> 2;                    // 0..1 (row half)
    const int wn = wv & 3;                     // 0..3 (col quarter)

    const short* Ag = (const short*)A + (size_t)(by << 8) * K;
    const short* Bg = (const short*)Bt + (size_t)(bx << 8) * K;

    const int swz = l15 & 7;
    const int aBase = ((wm << 7) + l15) << 6;  // (wm*128 + l15) * 64
    const int bBase = ((wn << 6) + l15) << 6;  // (wn*64  + l15) * 64
    const int cOff0 = (q ^ swz) << 3;
    const int cOff1 = ((q + 4) ^ swz) << 3;

    floatx4 acc[8][4];
#pragma unroll
    for (int i = 0; i < 8; ++i)
#pragma unroll
        for (int j = 0; j < 4; ++j)
            acc[i][j] = (floatx4){0.f, 0.f, 0.f, 0.f};

    const int nt = K >> 6;                     // 32 K-tiles of 64

    // prologue: T0 full (8 loads) + T1 {A-part1, B-full} (6 loads); wait T0.
    stage512(A0s, Ag, K, 0, 0,    wv, lane);
    stage512(A0s, Ag, K, 0, 512,  wv, lane);
    stage512(A0s, Ag, K, 0, 1024, wv, lane);
    stage512(A0s, Ag, K, 0, 1536, wv, lane);
    stage512(B0s, Bg, K, 0, 0,    wv, lane);
    stage512(B0s, Bg, K, 0, 512,  wv, lane);
    stage512(B0s, Bg, K, 0, 1024, wv, lane);
    stage512(B0s, Bg, K, 0, 1536, wv, lane);
    stage512(A1s, Ag, K, 64, 0,    wv, lane);
    stage512(A1s, Ag, K, 64, 1024, wv, lane);
    stage512(B1s, Bg, K, 64, 0,    wv, lane);
    stage512(B1s, Bg, K, 64, 512,  wv, lane);
    stage512(B1s, Bg, K, 64, 1024, wv, lane);
    stage512(B1s, Bg, K, 64, 1536, wv, lane);
    __builtin_amdgcn_sched_barrier(0);
    asm volatile("s_waitcnt vmcnt(6)" ::: "memory");   // T0 resident
    __builtin_amdgcn_s_barrier();

    for (int t = 0; t < nt; t += 2) {
        tile256(A0s, B0s, A1s, Ag, Bg, K, nt, t,     wv, lane, aBase, bBase, cOff0, cOff1, acc);
        tile256(A1s, B1s, A0s, Ag, Bg, K, nt, t + 1, wv, lane, aBase, bBase, cOff0, cOff1, acc);
    }

    // epilogue: C/D layout col = lane&15, row = quad*4 + reg (m89-verified)
#pragma unroll
    for (int mi = 0; mi < 8; ++mi)
#pragma unroll
        for (int ni = 0; ni < 4; ++ni)
#pragma unroll
            for (int r = 0; r < 4; ++r) {
                const int row = (by << 8) + (wm << 7) + (mi << 4) + (q << 2) + r;
                const int col = (bx << 8) + (wn << 6) + (ni << 4) + l15;
                C[(size_t)row * Nc + col] = acc[mi][ni][r];
            }
}

// ---------------- Tier-B (round-2 proven) manual-staging GEMM ----------------
template <int EPI, bool AF32, bool OF32>
__launch_bounds__(256, 2) __global__
void gemm_bt(const void* __restrict__ Ap, const bf16* __restrict__ Bt,
             void* __restrict__ Cp, const int Nc, const int K,
             const bf16* __restrict__ add1, const bf16* __restrict__ add2,
             const float* __restrict__ thetaP)
{
    __shared__ __attribute__((aligned(16))) short aT[128 * 32];
    __shared__ __attribute__((aligned(16))) short bT[128 * 32];

    const int nblk = Nc >> 7;
    const int bx = blockIdx.x % nblk;
    const int by = blockIdx.x / nblk;
    const int tid = threadIdx.x;
    const int lane = tid & 63;
    const int quad = lane >> 4;
    const int l15 = lane & 15;
    const int wv = tid >> 6;
    const int wr = (wv >> 1) << 6;
    const int wc = (wv & 1) << 6;

    const short* Ag = (const short*)Ap + (size_t)(by << 7) * K;
    const float* Agf = (const float*)Ap + (size_t)(by << 7) * K;
    const short* Bg = (const short*)Bt + (size_t)(bx << 7) * K;

    floatx4 acc[4][4];
#pragma unroll
    for (int i = 0; i < 4; ++i)
#pragma unroll
        for (int j = 0; j < 4; ++j)
            acc[i][j] = (floatx4){0.f, 0.f, 0.f, 0.f};

    for (int k0 = 0; k0 < K; k0 += 32) {
#pragma unroll
        for (int c = 0; c < 2; ++c) {
            const int ch = tid + (c << 8);
            const int row = ch >> 2;
            const int kp = (ch & 3) << 3;
            if (AF32) {
                const float4 f0 = *(const float4*)(Agf + (size_t)row * K + k0 + kp);
                const float4 f1 = *(const float4*)(Agf + (size_t)row * K + k0 + kp + 4);
                short8 pk;
                pk[0] = __builtin_bit_cast(short, __float2bfloat16(f0.x));
                pk[1] = __builtin_bit_cast(short, __float2bfloat16(f0.y));
                pk[2] = __builtin_bit_cast(short, __float2bfloat16(f0.z));
                pk[3] = __builtin_bit_cast(short, __float2bfloat16(f0.w));
                pk[4] = __builtin_bit_cast(short, __float2bfloat16(f1.x));
                pk[5] = __builtin_bit_cast(short, __float2bfloat16(f1.y));
                pk[6] = __builtin_bit_cast(short, __float2bfloat16(f1.z));
                pk[7] = __builtin_bit_cast(short, __float2bfloat16(f1.w));
                *(short8*)(aT + (row << 5) + kp) = pk;
            } else {
                *(int4*)(aT + (row << 5) + kp) = *(const int4*)(Ag + (size_t)row * K + k0 + kp);
            }
            *(int4*)(bT + (row << 5) + kp) = *(const int4*)(Bg + (size_t)row * K + k0 + kp);
        }
        __syncthreads();
        short8 af[4], bfr[4];
#pragma unroll
        for (int mi = 0; mi < 4; ++mi)
            af[mi] = *(const short8*)(aT + ((wr + (mi << 4) + l15) << 5) + (quad << 3));
#pragma unroll
        for (int ni = 0; ni < 4; ++ni)
            bfr[ni] = *(const short8*)(bT + ((wc + (ni << 4) + l15) << 5) + (quad << 3));
#pragma unroll
        for (int mi = 0; mi < 4; ++mi)
#pragma unroll
            for (int ni = 0; ni < 4; ++ni)
                acc[mi][ni] = __builtin_amdgcn_mfma_f32_16x16x32_bf16(af[mi], bfr[ni], acc[mi][ni], 0, 0, 0);
        __syncthreads();
    }

    float ct = 0.f, st = 0.f;
    if (EPI == EPI_P_ROT) {
        const float th = *thetaP;
        ct = cosf(th);
        st = sinf(th);
    }

#pragma unroll
    for (int mi = 0; mi < 4; ++mi) {
#pragma unroll
        for (int ni = 0; ni < 4; ++ni) {
#pragma unroll
            for (int r = 0; r < 4; ++r) {
                const int row = (by << 7) + wr + (mi << 4) + (quad << 2) + r;
                const int col = (bx << 7) + wc + (ni << 4) + l15;
                const size_t idx = (size_t)row * Nc + col;
                float v = acc[mi][ni][r];
                if (EPI == EPI_NEG) v = -v;
                if (EPI == EPI_ADD1) v += __bfloat162float(add1[idx]);
                if (EPI == EPI_P || EPI == EPI_P_ROT)
                    v += (row == col ? 1.f : 0.f)
                       + __bfloat162float(add1[idx]) + __bfloat162float(add2[idx]);
                if (EPI == EPI_P_ROT) {
                    const float w = __shfl_xor(v, 1, 64);
                    v = (l15 & 1) ? (st * w + ct * v) : (ct * v - st * w);
                }
                if (OF32) ((float*)Cp)[idx] = v;
                else      ((bf16*)Cp)[idx] = __float2bfloat16(v);
            }
        }
    }
}

// ---------------- launch ----------------
// out = x @ P1 @ R @ P2,  P = (I+M)^2 (I+M^2+M^4),  M = 0.5(W^T - W)
// Tier A: dual-batched chains; third dual now uses EPI_P with an explicit
//   HoffT buffer (bit-exact Hoff^T since M is skew) instead of EPI_PT's
//   transposed (uncoalesced) add2 read.  Skew/hoff builds merged+vectorized.
//   Final big GEMM: 256^2/BK=64/8-phase (R3-frozen) + XCD swizzle.
// Tier B: round-2 proven sequence.

extern "C" void kernel_launch(void* const* d_in, const int* in_sizes, int n_in,
                              void* d_out, int out_size, void* d_ws, size_t ws_size,
                              hipStream_t stream)
{
    const float* x = (const float*)d_in[0];
    const float* u1 = (const float*)d_in[1];
    const float* u2 = (const float*)d_in[2];
    const float* th = (const float*)d_in[3];
    float* out = (float*)d_out;
    const int tokens = in_sizes[0] / ND;

    const size_t MAT = (size_t)ND * ND;
    const size_t XBE = (size_t)tokens * ND;

    const dim3 blk(256);
    const int gSkew = (ND / 32) * (ND / 32);
    const int gElem = (int)(MAT / 256);
    const int gSm = (ND / 128) * (ND / 128);        // 256
    const int gBig = (tokens / 128) * (ND / 128);   // 2048

    if (ws_size >= (6 * MAT + XBE) * sizeof(bf16)) {
        // ---------------- Tier A ----------------
        bf16* base = (bf16*)d_ws;
        bf16* b0 = base;            // M2 -> HoffT2 -> P2T
        bf16* b1 = base + MAT;      // M1 -> P1R
        bf16* b2 = base + 2 * MAT;  // Msq2 -> Hoff2 -> QT
        bf16* b3 = base + 3 * MAT;  // Msq1 -> Hoff1
        bf16* b4 = base + 4 * MAT;  // Goff2
        bf16* b5 = base + 5 * MAT;  // Goff1
        bf16* xb = base + 6 * MAT;  // x as bf16

        convert_f32_bf16<<<(int)(XBE / 2048), blk, 0, stream>>>(x, xb);
        // M2 -> b0, M1 -> b1 (one dispatch)
        build_skew2<<<2 * gSkew, blk, 0, stream>>>(u2, b0, u1, b1);
        // Msq = -(M @ M^T) = M^2  (M skew)
        gemm_dual<EPI_NEG, EPI_NEG><<<2 * gSm, blk, 0, stream>>>(
            b0, b0, b2, nullptr, nullptr,  b1, b1, b3, nullptr, nullptr, nullptr);
        // Goff = Msq@Msq + Msq   (Msq symmetric)
        gemm_dual<EPI_ADD1, EPI_ADD1><<<2 * gSm, blk, 0, stream>>>(
            b2, b2, b4, b2, nullptr,  b3, b3, b5, b3, nullptr, nullptr);
        // Hoff2 = 2M2+Msq2 -> b2 ; HoffT2 = Msq2-2M2 -> b0 (== Hoff2^T, bit-exact)
        // Hoff1 = 2M1+Msq1 -> b3                       (one dispatch, x8 vectorized)
        build_hoffs<<<(int)(2 * MAT / 2048), blk, 0, stream>>>(b0, b2, b2, b0, b1, b3, b3);
        // P2T = Goff2@Hoff2^T + I + Goff2 + HoffT2  (all coalesced reads now)
        // P1R = (Hoff1@Goff1 + I + Goff1 + Hoff1) @ R
        gemm_dual<EPI_P, EPI_P_ROT><<<2 * gSm, blk, 0, stream>>>(
            b4, b2, b0, b4, b0,  b3, b5, b1, b5, b3, th);
        // QT = P2T @ (P1R)^T
        gemm_one<EPI_PLAIN, false><<<gSm, blk, 0, stream>>>(b0, b1, b2, ND, ND, nullptr, nullptr, nullptr);
        // out = x @ QT^T  -- 256x256 8-phase kernel (fallback: old 128x128 path)
        if ((tokens & 255) == 0) {
            const int gBig256 = (tokens >> 8) * (ND >> 8);   // 512
            gemm_big256<<<gBig256, dim3(512), 0, stream>>>(xb, b2, out, ND, ND);
        } else {
            gemm_one<EPI_PLAIN, true><<<gBig, blk, 0, stream>>>(xb, b2, out, ND, ND, nullptr, nullptr, nullptr);
        }
    } else {
        // ---------------- Tier B (round-2 proven) ----------------
        bf16* A = (bf16*)d_ws;
        bf16* B = A + MAT;
        bf16* Cb = B + MAT;
        bf16* D = Cb + MAT;
        bf16* E = D + MAT;

        build_skew2<<<gSkew, blk, 0, stream>>>(u2, A, u2, A);   // single-matrix use
        gemm_bt<EPI_NEG, false, false><<<gSm, blk, 0, stream>>>(A, A, B, ND, ND, nullptr, nullptr, nullptr);
        gemm_bt<EPI_ADD1, false, false><<<gSm, blk, 0, stream>>>(B, B, Cb, ND, ND, B, nullptr, nullptr);
        build_hoff<<<gElem, blk, 0, stream>>>(A, B, D, E);
        gemm_bt<EPI_P, false, false><<<gSm, blk, 0, stream>>>(Cb, D, A, ND, ND, Cb, E, nullptr);

        build_skew2<<<gSkew, blk, 0, stream>>>(u1, B, u1, B);
        gemm_bt<EPI_NEG, false, false><<<gSm, blk, 0, stream>>>(B, B, Cb, ND, ND, nullptr, nullptr, nullptr);
        gemm_bt<EPI_ADD1, false, false><<<gSm, blk, 0, stream>>>(Cb, Cb, D, ND, ND, Cb, nullptr, nullptr);
        build_hoff<<<gElem, blk, 0, stream>>>(B, Cb, E, B);
        gemm_bt<EPI_P_ROT, false, false><<<gSm, blk, 0, stream>>>(E, D, Cb, ND, ND, D, E, th);

        gemm_bt<EPI_PLAIN, false, false><<<gSm, blk, 0, stream>>>(A, Cb, D, ND, ND, nullptr, nullptr, nullptr);
        gemm_bt<EPI_PLAIN, true, true><<<gBig, blk, 0, stream>>>(x, D, out, ND, ND, nullptr, nullptr, nullptr);
    }
}